// Round 1
// baseline (806.320 us; speedup 1.0000x reference)
//
#include <hip/hip_runtime.h>
#include <math.h>

// ---------- types & helpers ----------
typedef __bf16 bf16x8 __attribute__((ext_vector_type(8)));
typedef unsigned short u16x8 __attribute__((ext_vector_type(8)));
typedef float f32x4 __attribute__((ext_vector_type(4)));

__device__ __forceinline__ float bf2f(unsigned short u) {
  union { unsigned u; float f; } v; v.u = ((unsigned)u) << 16; return v.f;
}
__device__ __forceinline__ unsigned short f2bf(float f) {
  union { float f; unsigned u; } v; v.f = f;
  unsigned r = v.u + 0x7fffu + ((v.u >> 16) & 1u);
  return (unsigned short)(r >> 16);
}
__device__ __forceinline__ bf16x8 ld8(const unsigned short* p) {
  return __builtin_bit_cast(bf16x8, *(const u16x8*)p);
}
__device__ __forceinline__ bf16x8 ld8f(const float* p) {
  f32x4 a = *(const f32x4*)p;
  f32x4 b = *(const f32x4*)(p + 4);
  u16x8 u;
#pragma unroll
  for (int i = 0; i < 4; ++i) { u[i] = f2bf(a[i]); u[4 + i] = f2bf(b[i]); }
  return __builtin_bit_cast(bf16x8, u);
}
// dtype-adaptive loads/stores (isf: 1 = buffers are f32, 0 = bf16)
__device__ __forceinline__ float ldS(const void* p, int isf, size_t i) {
  return isf ? ((const float*)p)[i] : bf2f(((const unsigned short*)p)[i]);
}
__device__ __forceinline__ bf16x8 ld8G(const void* p, int isf, size_t i) {
  return isf ? ld8f((const float*)p + i) : ld8((const unsigned short*)p + i);
}
__device__ __forceinline__ void stO(void* p, int isf, size_t i, float v) {
  if (isf) ((float*)p)[i] = v; else ((unsigned short*)p)[i] = f2bf(v);
}
__device__ __forceinline__ bf16x8 zero8() {
  u16x8 z;
#pragma unroll
  for (int i = 0; i < 8; ++i) z[i] = 0;
  return __builtin_bit_cast(bf16x8, z);
}
__device__ __forceinline__ f32x4 fzero4() {
  f32x4 z; z[0] = z[1] = z[2] = z[3] = 0.f; return z;
}
__device__ __forceinline__ f32x4 mfma16(bf16x8 a, bf16x8 b, f32x4 c) {
  return __builtin_amdgcn_mfma_f32_16x16x32_bf16(a, b, c, 0, 0, 0);
}
__device__ __forceinline__ float scrub(float v) {
  return fminf(fmaxf(v, -1e6f), 1e6f);
}

#define C_DIM 96
#define NTOK 128
#define XO_STR 104
#define PSTR 136          // scratch V^T/P row stride (u16): 272B = 17*16, aligned + spread
#define SCR 2176          // per-wave scratch u16 count = max(128*16, 16*136)
#define Z_STR 104
#define H_STR 392
#define NTOK2 64          // MLP tokens per block (halved for 2 blocks/CU)

// =====================================================================
// dtype sniffer (unchanged)
__global__ void dtype_sniff(const unsigned short* __restrict__ x, int* __restrict__ flag) {
  int lane = threadIdx.x;  // 64 threads
  int weird = 0;
#pragma unroll
  for (int k = 0; k < 4; ++k) {
    unsigned short w = x[lane * 4 + k];
    int e = (w >> 7) & 0xFF;
    if (e >= 0xC0 || (e != 0 && e <= 0x30)) weird++;
  }
#pragma unroll
  for (int d = 1; d < 64; d <<= 1) weird += __shfl_xor(weird, d, 64);
  if (lane == 0) *flag = (weird > 16) ? 1 : 0;
}

// =====================================================================
// Kernel A: LN1 + shift + window attention + proj + residual -> y
// one block (384 thr = 6 waves) per window; 2048 windows.
// LDS = 78,336 B  -> 2 blocks/CU (was 132,608 -> 1 block/CU).
// Per-wave = per-head: each wave computes its OWN head's Q,K,V, so K/V
// transpose through a wave-private scratch (no barriers) into registers,
// and stage 3 runs barrier-free.
// =====================================================================
__global__ __launch_bounds__(384, 3) void swin_attn_kernel(
    const void* __restrict__ x,
    const void* __restrict__ g1,
    const void* __restrict__ b1,
    const void* __restrict__ w_qkv,
    const void* __restrict__ b_qkv,
    const void* __restrict__ w_proj,
    const void* __restrict__ b_proj,
    void* __restrict__ y,
    const int* __restrict__ flag)
{
  __shared__ __align__(16) unsigned short sm_xo[NTOK * XO_STR];   // LN out, then attn out
  __shared__ __align__(16) unsigned short sm_q[6 * NTOK * 16];    // per-head Q [head][tok][16]
  __shared__ __align__(16) unsigned short sm_scr[6 * SCR];        // per-wave: K^ / V^T / P
  __shared__ int sm_tok[NTOK];
  __shared__ int sm_cls[NTOK];
  float* sm_red = (float*)sm_scr;  // stage-1 alias: [2][3][NTOK]; scr first written in stage 2

  const int isf = *flag;
  const int tid = threadIdx.x;
  const int win = blockIdx.x;
  const int b = win >> 10;
  const int rem = win & 1023;
  const int ti = rem >> 8, hi = (rem >> 4) & 15, wi = rem & 15;

  // ---- Stage 1: gather (cyclic shift) + LN1 ----
  {
    const int n = tid & 127;
    const int part = tid >> 7;
    const int td = n >> 6, hh = (n >> 3) & 7, ww = n & 7;
    const int t = ti * 2 + td, h = hi * 8 + hh, w = wi * 8 + ww;
    const int ts = (t + 1) & 7, hs = (h + 4) & 127, ws = (w + 4) & 127;
    const int tok = ((b * 8 + ts) * 128 + hs) * 128 + ws;
    if (part == 0) {
      sm_tok[n] = tok;
      int ct = (t < 6) ? 0 : (t - 5);
      int ch = (h < 120) ? 0 : ((h < 124) ? 1 : 2);
      int cw = (w < 120) ? 0 : ((w < 124) ? 1 : 2);
      sm_cls[n] = ct * 9 + ch * 3 + cw;
    }
    float v[32];
    if (isf) {
      const float* xp = (const float*)x + (size_t)tok * C_DIM + part * 32;
      f32x4 raw[8];
#pragma unroll
      for (int i = 0; i < 8; ++i) raw[i] = ((const f32x4*)xp)[i];
#pragma unroll
      for (int i = 0; i < 32; ++i) v[i] = raw[i >> 2][i & 3];
    } else {
      const unsigned short* xp = (const unsigned short*)x + (size_t)tok * C_DIM + part * 32;
      u16x8 raw[4];
#pragma unroll
      for (int i = 0; i < 4; ++i) raw[i] = ((const u16x8*)xp)[i];
#pragma unroll
      for (int i = 0; i < 32; ++i) v[i] = bf2f(raw[i >> 3][i & 7]);
    }
    float s = 0.f, s2 = 0.f;
#pragma unroll
    for (int i = 0; i < 32; ++i) {
      v[i] = scrub(v[i]);
      s += v[i]; s2 += v[i] * v[i];
    }
    sm_red[part * NTOK + n] = s;
    sm_red[(3 + part) * NTOK + n] = s2;
    __syncthreads();
    float tsum = sm_red[0 * NTOK + n] + sm_red[1 * NTOK + n] + sm_red[2 * NTOK + n];
    float tsq  = sm_red[3 * NTOK + n] + sm_red[4 * NTOK + n] + sm_red[5 * NTOK + n];
    float mean = tsum * (1.0f / 96.0f);
    float var = fmaxf(tsq * (1.0f / 96.0f) - mean * mean, 0.0f);
    float rstd = rsqrtf(var + 1e-5f);
#pragma unroll
    for (int i = 0; i < 32; ++i) {
      int c = part * 32 + i;
      sm_xo[n * XO_STR + c] = f2bf((v[i] - mean) * rstd * ldS(g1, isf, c) + ldS(b1, isf, c));
    }
  }
  __syncthreads();

  const int wv = tid >> 6;
  const int lane = tid & 63;
  const int quad = lane >> 4;
  const int l16 = lane & 15;
  unsigned short* scr = sm_scr + wv * SCR;          // wave-private scratch
  unsigned short* qh  = sm_q + wv * (NTOK * 16);    // this head's Q

  // ---- Stage 2: per-wave per-head QKV GEMM (M=128, K=96) ----
  bf16x8 bk[8], bv[4];
  {
    // ---- Q (scaled by 0.25) -> sm_q[head][tok][16] ----
    {
      const int jcol = wv * 16 + l16;
      bf16x8 bw[3];
#pragma unroll
      for (int kt = 0; kt < 3; ++kt)
        bw[kt] = ld8G(w_qkv, isf, (size_t)jcol * C_DIM + kt * 32 + quad * 8);
      const float bias = ldS(b_qkv, isf, jcol);
      for (int mt = 0; mt < 8; ++mt) {
        f32x4 acc = fzero4();
#pragma unroll
        for (int kt = 0; kt < 3; ++kt)
          acc = mfma16(ld8(sm_xo + (mt * 16 + l16) * XO_STR + kt * 32 + quad * 8), bw[kt], acc);
#pragma unroll
        for (int r = 0; r < 4; ++r)
          qh[(mt * 16 + quad * 4 + r) * 16 + l16] = f2bf((acc[r] + bias) * 0.25f);
      }
    }
    // ---- K -> scratch [tok][16], then into regs (intra-wave, no barrier) ----
    {
      const int jcol = C_DIM + wv * 16 + l16;
      bf16x8 bw[3];
#pragma unroll
      for (int kt = 0; kt < 3; ++kt)
        bw[kt] = ld8G(w_qkv, isf, (size_t)jcol * C_DIM + kt * 32 + quad * 8);
      const float bias = ldS(b_qkv, isf, jcol);
      for (int mt = 0; mt < 8; ++mt) {
        f32x4 acc = fzero4();
#pragma unroll
        for (int kt = 0; kt < 3; ++kt)
          acc = mfma16(ld8(sm_xo + (mt * 16 + l16) * XO_STR + kt * 32 + quad * 8), bw[kt], acc);
#pragma unroll
        for (int r = 0; r < 4; ++r)
          scr[(mt * 16 + quad * 4 + r) * 16 + l16] = f2bf(acc[r] + bias);
      }
    }
#pragma unroll
    for (int nt = 0; nt < 8; ++nt)
      bk[nt] = (quad < 2) ? ld8(scr + (nt * 16 + l16) * 16 + quad * 8) : zero8();
    // ---- V -> scratch transposed [dim][tok] (stride PSTR), then into regs ----
    {
      const int jcol = 2 * C_DIM + wv * 16 + l16;
      bf16x8 bw[3];
#pragma unroll
      for (int kt = 0; kt < 3; ++kt)
        bw[kt] = ld8G(w_qkv, isf, (size_t)jcol * C_DIM + kt * 32 + quad * 8);
      const float bias = ldS(b_qkv, isf, jcol);
      for (int mt = 0; mt < 8; ++mt) {
        f32x4 acc = fzero4();
#pragma unroll
        for (int kt = 0; kt < 3; ++kt)
          acc = mfma16(ld8(sm_xo + (mt * 16 + l16) * XO_STR + kt * 32 + quad * 8), bw[kt], acc);
#pragma unroll
        for (int r = 0; r < 4; ++r)
          scr[l16 * PSTR + (mt * 16 + quad * 4 + r)] = f2bf(acc[r] + bias);
      }
    }
#pragma unroll
    for (int kt = 0; kt < 4; ++kt)
      bv[kt] = ld8(scr + l16 * PSTR + kt * 32 + quad * 8);
  }
  // all sm_xo reads are done above; after this barrier sm_xo becomes attn-out
  __syncthreads();

  // ---- Stage 3: attention, one head per wave — barrier-free ----
  for (int mt = 0; mt < 8; ++mt) {
    bf16x8 aq = (quad < 2) ? ld8(qh + (mt * 16 + l16) * 16 + quad * 8) : zero8();
    f32x4 s[8];
#pragma unroll
    for (int nt = 0; nt < 8; ++nt) s[nt] = mfma16(aq, bk[nt], fzero4());
    int ccls[8];
#pragma unroll
    for (int nt = 0; nt < 8; ++nt) ccls[nt] = sm_cls[nt * 16 + l16];
#pragma unroll
    for (int r = 0; r < 4; ++r) {
      int rc = sm_cls[mt * 16 + quad * 4 + r];
#pragma unroll
      for (int nt = 0; nt < 8; ++nt)
        if (ccls[nt] != rc) s[nt][r] += -100.0f;
    }
#pragma unroll
    for (int r = 0; r < 4; ++r) {
      float m = s[0][r];
#pragma unroll
      for (int nt = 1; nt < 8; ++nt) m = fmaxf(m, s[nt][r]);
#pragma unroll
      for (int d = 1; d < 16; d <<= 1) m = fmaxf(m, __shfl_xor(m, d, 64));
      float e[8], sum = 0.f;
#pragma unroll
      for (int nt = 0; nt < 8; ++nt) { e[nt] = __expf(s[nt][r] - m); sum += e[nt]; }
#pragma unroll
      for (int d = 1; d < 16; d <<= 1) sum += __shfl_xor(sum, d, 64);
      float inv = 1.0f / sum;
#pragma unroll
      for (int nt = 0; nt < 8; ++nt)
        scr[(quad * 4 + r) * PSTR + nt * 16 + l16] = f2bf(e[nt] * inv);
    }
    // wave-private P: no __syncthreads needed (compiler inserts lgkmcnt)
    f32x4 o = fzero4();
#pragma unroll
    for (int kt = 0; kt < 4; ++kt)
      o = mfma16(ld8(scr + l16 * PSTR + kt * 32 + quad * 8), bv[kt], o);
#pragma unroll
    for (int r = 0; r < 4; ++r)
      sm_xo[(mt * 16 + quad * 4 + r) * XO_STR + wv * 16 + l16] = f2bf(o[r]);
  }
  __syncthreads();

  // ---- Stage 4: proj + residual + scatter ----
  {
    const int jcol = wv * 16 + l16;
    bf16x8 bp[3];
#pragma unroll
    for (int kt = 0; kt < 3; ++kt)
      bp[kt] = ld8G(w_proj, isf, (size_t)jcol * C_DIM + kt * 32 + quad * 8);
    const float bias = ldS(b_proj, isf, jcol);
    for (int mt = 0; mt < 8; ++mt) {
      f32x4 acc = fzero4();
#pragma unroll
      for (int kt = 0; kt < 3; ++kt) {
        bf16x8 a = ld8(sm_xo + (mt * 16 + l16) * XO_STR + kt * 32 + quad * 8);
        acc = mfma16(a, bp[kt], acc);
      }
#pragma unroll
      for (int r = 0; r < 4; ++r) {
        int row = mt * 16 + quad * 4 + r;
        size_t addr = (size_t)sm_tok[row] * C_DIM + jcol;
        stO(y, isf, addr, scrub(ldS(x, isf, addr)) + acc[r] + bias);
      }
    }
  }
}

// =====================================================================
// Kernel B: LN2 + fc1 + GELU + fc2 + residual; y in d_out, in place.
// 64 tokens/block (LDS 63,488 B -> 2 blocks/CU), 4096 blocks.
// =====================================================================
__global__ __launch_bounds__(384, 3) void swin_mlp_kernel(
    const void* __restrict__ g2,
    const void* __restrict__ b2,
    const void* __restrict__ w_fc1,
    const void* __restrict__ b_fc1,
    const void* __restrict__ w_fc2,
    const void* __restrict__ b_fc2,
    void* __restrict__ yout,
    const int* __restrict__ flag)
{
  __shared__ __align__(16) unsigned short sm_z[NTOK2 * Z_STR];
  __shared__ __align__(16) unsigned short sm_h[NTOK2 * H_STR];
  float* sm_red = (float*)sm_h;  // stage-1 alias: [2][6][NTOK2]; sm_h first written post-barrier

  const int isf = *flag;
  const int tid = threadIdx.x;
  const size_t tok0 = (size_t)blockIdx.x * NTOK2;

  // ---- LN2 ---- (64 tokens x 6 parts of 16 channels)
  {
    const int n = tid & 63;
    const int part = tid >> 6;  // 0..5
    float v[16];
    if (isf) {
      const float* yp = (const float*)yout + (tok0 + n) * C_DIM + part * 16;
      f32x4 raw[4];
#pragma unroll
      for (int i = 0; i < 4; ++i) raw[i] = ((const f32x4*)yp)[i];
#pragma unroll
      for (int i = 0; i < 16; ++i) v[i] = raw[i >> 2][i & 3];
    } else {
      const unsigned short* yp = (const unsigned short*)yout + (tok0 + n) * C_DIM + part * 16;
      u16x8 raw[2];
#pragma unroll
      for (int i = 0; i < 2; ++i) raw[i] = ((const u16x8*)yp)[i];
#pragma unroll
      for (int i = 0; i < 16; ++i) v[i] = bf2f(raw[i >> 3][i & 7]);
    }
    float s = 0.f, s2 = 0.f;
#pragma unroll
    for (int i = 0; i < 16; ++i) { s += v[i]; s2 += v[i] * v[i]; }
    sm_red[part * NTOK2 + n] = s;
    sm_red[(6 + part) * NTOK2 + n] = s2;
    __syncthreads();
    float tsum = 0.f, tsq = 0.f;
#pragma unroll
    for (int p = 0; p < 6; ++p) {
      tsum += sm_red[p * NTOK2 + n];
      tsq  += sm_red[(6 + p) * NTOK2 + n];
    }
    float mean = tsum * (1.0f / 96.0f);
    float var = fmaxf(tsq * (1.0f / 96.0f) - mean * mean, 0.0f);
    float rstd = rsqrtf(var + 1e-5f);
#pragma unroll
    for (int i = 0; i < 16; ++i) {
      int c = part * 16 + i;
      sm_z[n * Z_STR + c] = f2bf((v[i] - mean) * rstd * ldS(g2, isf, c) + ldS(b2, isf, c));
    }
  }
  __syncthreads();

  const int wv = tid >> 6;
  const int lane = tid & 63;
  const int quad = lane >> 4;
  const int l16 = lane & 15;

  // ---- fc1 + exact GELU ----
  {
#pragma unroll
    for (int nt4 = 0; nt4 < 4; ++nt4) {
      const int jcol = (wv * 4 + nt4) * 16 + l16;
      bf16x8 bw[3];
#pragma unroll
      for (int kt = 0; kt < 3; ++kt)
        bw[kt] = ld8G(w_fc1, isf, (size_t)jcol * C_DIM + kt * 32 + quad * 8);
      const float bias = ldS(b_fc1, isf, jcol);
      for (int mt = 0; mt < 4; ++mt) {
        f32x4 acc = fzero4();
#pragma unroll
        for (int kt = 0; kt < 3; ++kt) {
          bf16x8 a = ld8(sm_z + (mt * 16 + l16) * Z_STR + kt * 32 + quad * 8);
          acc = mfma16(a, bw[kt], acc);
        }
#pragma unroll
        for (int r = 0; r < 4; ++r) {
          float hv = acc[r] + bias;
          float g = 0.5f * hv * (1.0f + erff(hv * 0.70710678118654752f));
          sm_h[(mt * 16 + quad * 4 + r) * H_STR + jcol] = f2bf(g);
        }
      }
    }
  }
  __syncthreads();

  // ---- fc2 + residual ----
  {
    const int jcol = wv * 16 + l16;
    bf16x8 bw[12];
#pragma unroll
    for (int kt = 0; kt < 12; ++kt)
      bw[kt] = ld8G(w_fc2, isf, (size_t)jcol * 384 + kt * 32 + quad * 8);
    const float bias = ldS(b_fc2, isf, jcol);
    for (int mt = 0; mt < 4; ++mt) {
      f32x4 acc = fzero4();
#pragma unroll
      for (int kt = 0; kt < 12; ++kt) {
        bf16x8 a = ld8(sm_h + (mt * 16 + l16) * H_STR + kt * 32 + quad * 8);
        acc = mfma16(a, bw[kt], acc);
      }
#pragma unroll
      for (int r = 0; r < 4; ++r) {
        int row = mt * 16 + quad * 4 + r;
        size_t addr = (tok0 + row) * C_DIM + jcol;
        stO(yout, isf, addr, ldS(yout, isf, addr) + acc[r] + bias);
      }
    }
  }
}

// =====================================================================
extern "C" void kernel_launch(void* const* d_in, const int* in_sizes, int n_in,
                              void* d_out, int out_size, void* d_ws, size_t ws_size,
                              hipStream_t stream) {
  const void* x      = d_in[0];
  // d_in[1] = attn_mask (recomputed analytically; unused)
  const void* g1     = d_in[2];
  const void* b1     = d_in[3];
  const void* w_qkv  = d_in[4];
  const void* b_qkv  = d_in[5];
  const void* w_proj = d_in[6];
  const void* b_proj = d_in[7];
  const void* g2     = d_in[8];
  const void* b2     = d_in[9];
  const void* w_fc1  = d_in[10];
  const void* b_fc1  = d_in[11];
  const void* w_fc2  = d_in[12];
  const void* b_fc2  = d_in[13];
  int* flag = (int*)d_ws;

  dtype_sniff<<<1, 64, 0, stream>>>((const unsigned short*)x, flag);
  swin_attn_kernel<<<2048, 384, 0, stream>>>(x, g1, b1, w_qkv, b_qkv, w_proj, b_proj, d_out, flag);
  swin_mlp_kernel<<<4096, 384, 0, stream>>>(g2, b2, w_fc1, b_fc1, w_fc2, b_fc2, d_out, flag);
}

// Round 3
// 695.112 us; speedup vs baseline: 1.1600x; 1.1600x over previous
//
#include <hip/hip_runtime.h>
#include <math.h>

// ---------- types & helpers ----------
typedef __bf16 bf16x8 __attribute__((ext_vector_type(8)));
typedef unsigned short u16x8 __attribute__((ext_vector_type(8)));
typedef unsigned short u16x4 __attribute__((ext_vector_type(4)));
typedef float f32x4 __attribute__((ext_vector_type(4)));

__device__ __forceinline__ float bf2f(unsigned short u) {
  union { unsigned u; float f; } v; v.u = ((unsigned)u) << 16; return v.f;
}
__device__ __forceinline__ unsigned short f2bf(float f) {
  union { float f; unsigned u; } v; v.f = f;
  unsigned r = v.u + 0x7fffu + ((v.u >> 16) & 1u);
  return (unsigned short)(r >> 16);
}
__device__ __forceinline__ unsigned pk_bf16(float lo, float hi) {
  unsigned r;
  asm("v_cvt_pk_bf16_f32 %0, %1, %2" : "=v"(r) : "v"(lo), "v"(hi));
  return r;
}
// compiler-only memory fence: pins LDS store->load ordering for wave-private
// data exchanged without __syncthreads (DS pipe is in-order per wave; the
// only hazard is compiler reordering across TBAA classes).
__device__ __forceinline__ void cfence() { asm volatile("" ::: "memory"); }

__device__ __forceinline__ bf16x8 ld8(const unsigned short* p) {
  return __builtin_bit_cast(bf16x8, *(const u16x8*)p);
}
__device__ __forceinline__ bf16x8 ld8f(const float* p) {
  f32x4 a = *(const f32x4*)p;
  f32x4 b = *(const f32x4*)(p + 4);
  u16x8 u;
#pragma unroll
  for (int i = 0; i < 4; ++i) { u[i] = f2bf(a[i]); u[4 + i] = f2bf(b[i]); }
  return __builtin_bit_cast(bf16x8, u);
}
// dtype-adaptive loads/stores (isf: 1 = buffers are f32, 0 = bf16)
__device__ __forceinline__ float ldS(const void* p, int isf, size_t i) {
  return isf ? ((const float*)p)[i] : bf2f(((const unsigned short*)p)[i]);
}
__device__ __forceinline__ bf16x8 ld8G(const void* p, int isf, size_t i) {
  return isf ? ld8f((const float*)p + i) : ld8((const unsigned short*)p + i);
}
__device__ __forceinline__ void stO(void* p, int isf, size_t i, float v) {
  if (isf) ((float*)p)[i] = v; else ((unsigned short*)p)[i] = f2bf(v);
}
__device__ __forceinline__ bf16x8 zero8() {
  u16x8 z;
#pragma unroll
  for (int i = 0; i < 8; ++i) z[i] = 0;
  return __builtin_bit_cast(bf16x8, z);
}
__device__ __forceinline__ f32x4 fzero4() {
  f32x4 z; z[0] = z[1] = z[2] = z[3] = 0.f; return z;
}
__device__ __forceinline__ f32x4 mfma16(bf16x8 a, bf16x8 b, f32x4 c) {
  return __builtin_amdgcn_mfma_f32_16x16x32_bf16(a, b, c, 0, 0, 0);
}
__device__ __forceinline__ float scrub(float v) {
  return fminf(fmaxf(v, -1e6f), 1e6f);
}
// packed store of 8 bf16 (16B) via ushort-vector (same TBAA class as ld8)
__device__ __forceinline__ void st_pk8(unsigned short* p, const float* v) {
  uint4 w;
  w.x = pk_bf16(v[0], v[1]); w.y = pk_bf16(v[2], v[3]);
  w.z = pk_bf16(v[4], v[5]); w.w = pk_bf16(v[6], v[7]);
  *(u16x8*)p = __builtin_bit_cast(u16x8, w);
}
// packed store of 4 bf16 (8B) via ushort-vector
__device__ __forceinline__ void st_pk4(unsigned short* p, float a, float b, float c, float d) {
  uint2 w; w.x = pk_bf16(a, b); w.y = pk_bf16(c, d);
  *(u16x4*)p = __builtin_bit_cast(u16x4, w);
}
// fast exact-enough GELU: A&S 7.1.26 erf poly, |err(erf)| <= ~1.5e-7
__device__ __forceinline__ float gelu_f(float x) {
  float ax = fabsf(x);
  float t = __builtin_amdgcn_rcpf(1.0f + 0.3275911f * ax);
  float poly = t * (0.254829592f + t * (-0.284496736f + t * (1.421413741f +
               t * (-1.453152027f + t * 1.061405429f))));
  float er = 1.0f - poly * __expf(-ax * ax);
  er = copysignf(er, x);
  return 0.5f * x * (1.0f + er);
}

#define C_DIM 96
#define XO_STR 104   // LN-out row stride (u16)
#define QH_STR 24    // per-head [tok][24] stride (u16): 48B rows, b64/b128 aligned
#define VP_STR 136   // V^T / P row stride (u16): 272B
#define SCRW 2176    // per-wave scratch u16 (max of K-tmp 2048, V^T/P 2176)
#define QHW 3072     // per-head Q/attn-out u16 (128*24)

// =====================================================================
// dtype sniffer (unchanged)
__global__ void dtype_sniff(const unsigned short* __restrict__ x, int* __restrict__ flag) {
  int lane = threadIdx.x;  // 64 threads
  int weird = 0;
#pragma unroll
  for (int k = 0; k < 4; ++k) {
    unsigned short w = x[lane * 4 + k];
    int e = (w >> 7) & 0xFF;
    if (e >= 0xC0 || (e != 0 && e <= 0x30)) weird++;
  }
#pragma unroll
  for (int d = 1; d < 64; d <<= 1) weird += __shfl_xor(weird, d, 64);
  if (lane == 0) *flag = (weird > 16) ? 1 : 0;
}

// =====================================================================
// Kernel A: LN1 + shift + window attention + proj + residual -> y
// 2048 blocks x 384 thr (6 waves = 6 heads). LDS 64,520B -> 2 blocks/CU.
// Swapped-operand attention: S^T = K*Q^T so softmax is lane-local;
// Q/K produced transposed (packed b64 stores); P stays wave-private.
// =====================================================================
__global__ __launch_bounds__(384, 3) void swin_attn_kernel(
    const void* __restrict__ x,
    const void* __restrict__ g1,
    const void* __restrict__ b1,
    const void* __restrict__ w_qkv,
    const void* __restrict__ b_qkv,
    const void* __restrict__ w_proj,
    const void* __restrict__ b_proj,
    void* __restrict__ y,
    const int* __restrict__ flag)
{
  __shared__ __align__(16) unsigned short sm_A[13312];   // xo [128][104]; later 6x scratch
  __shared__ __align__(16) unsigned short sm_qB[18432];  // stage1: red; later 6x [128][24]
  __shared__ int sm_tok[128];
  __shared__ int sm_cls[128];
  __shared__ int sm_nu[2];
  float* sm_red = (float*)sm_qB;  // 768 floats, dead before Q written

  const int isf = *flag;
  const int tid = threadIdx.x;
  const int win = blockIdx.x;
  const int b = win >> 10;
  const int rem = win & 1023;
  const int ti = rem >> 8, hi = (rem >> 4) & 15, wi = rem & 15;

  // ---- Stage 1: gather (cyclic shift) + LN1 ----
  {
    const int n = tid & 127;
    const int part = tid >> 7;
    const int td = n >> 6, hh = (n >> 3) & 7, ww = n & 7;
    const int t = ti * 2 + td, h = hi * 8 + hh, w = wi * 8 + ww;
    const int ts = (t + 1) & 7, hs = (h + 4) & 127, ws = (w + 4) & 127;
    const int tok = ((b * 8 + ts) * 128 + hs) * 128 + ws;
    if (part == 0) {
      sm_tok[n] = tok;
      int ct = (t < 6) ? 0 : (t - 5);
      int ch = (h < 120) ? 0 : ((h < 124) ? 1 : 2);
      int cw = (w < 120) ? 0 : ((w < 124) ? 1 : 2);
      int cls = ct * 9 + ch * 3 + cw;
      sm_cls[n] = cls;
      // window-uniform-class flag (skip mask work on interior windows)
      int t0 = ti * 2;
      int ct0 = (t0 < 6) ? 0 : (t0 - 5);
      int ch0 = (hi < 15) ? 0 : 1;
      int cw0 = (wi < 15) ? 0 : 1;
      int cls0 = ct0 * 9 + ch0 * 3 + cw0;
      unsigned long long bal = __ballot(cls != cls0);
      if ((tid & 63) == 0) sm_nu[tid >> 6] = (bal != 0ULL) ? 1 : 0;
    }
    float v[32];
    if (isf) {
      const float* xp = (const float*)x + (size_t)tok * C_DIM + part * 32;
      f32x4 raw[8];
#pragma unroll
      for (int i = 0; i < 8; ++i) raw[i] = ((const f32x4*)xp)[i];
#pragma unroll
      for (int i = 0; i < 32; ++i) v[i] = raw[i >> 2][i & 3];
    } else {
      const unsigned short* xp = (const unsigned short*)x + (size_t)tok * C_DIM + part * 32;
      u16x8 raw[4];
#pragma unroll
      for (int i = 0; i < 4; ++i) raw[i] = ((const u16x8*)xp)[i];
#pragma unroll
      for (int i = 0; i < 32; ++i) v[i] = bf2f(raw[i >> 3][i & 7]);
    }
    float s = 0.f, s2 = 0.f;
#pragma unroll
    for (int i = 0; i < 32; ++i) {
      v[i] = scrub(v[i]);
      s += v[i]; s2 += v[i] * v[i];
    }
    sm_red[part * 128 + n] = s;
    sm_red[(3 + part) * 128 + n] = s2;
    __syncthreads();
    float tsum = sm_red[0 * 128 + n] + sm_red[1 * 128 + n] + sm_red[2 * 128 + n];
    float tsq  = sm_red[3 * 128 + n] + sm_red[4 * 128 + n] + sm_red[5 * 128 + n];
    float mean = tsum * (1.0f / 96.0f);
    float var = fmaxf(tsq * (1.0f / 96.0f) - mean * mean, 0.0f);
    float rstd = rsqrtf(var + 1e-5f);
    float o[32];
#pragma unroll
    for (int i = 0; i < 32; ++i) {
      int c = part * 32 + i;
      o[i] = (v[i] - mean) * rstd * ldS(g1, isf, c) + ldS(b1, isf, c);
    }
#pragma unroll
    for (int k = 0; k < 4; ++k)
      st_pk8(sm_A + n * XO_STR + part * 32 + k * 8, &o[k * 8]);
  }
  __syncthreads();

  const int wv = tid >> 6;
  const int lane = tid & 63;
  const int quad = lane >> 4;
  const int l16 = lane & 15;
  unsigned short* scr = sm_A + wv * SCRW;
  unsigned short* qh  = sm_qB + wv * QHW;

  // ---- preload A-fragments of LN-out (xw): row=tok on l16, k=c on quad ----
  bf16x8 az[3][8];
#pragma unroll
  for (int kt = 0; kt < 3; ++kt)
#pragma unroll
    for (int mt = 0; mt < 8; ++mt)
      az[kt][mt] = ld8(sm_A + (mt * 16 + l16) * XO_STR + kt * 32 + quad * 8);

  // ---- Q^T GEMM (W_q rows x xw^T): C col=tok(l16), row=d(quad,r); packed b64 ----
  {
    const int jrow = wv * 16 + l16;
    bf16x8 bw[3];
#pragma unroll
    for (int kt = 0; kt < 3; ++kt)
      bw[kt] = ld8G(w_qkv, isf, (size_t)jrow * C_DIM + kt * 32 + quad * 8);
    float bias[4];
#pragma unroll
    for (int r = 0; r < 4; ++r) bias[r] = ldS(b_qkv, isf, wv * 16 + quad * 4 + r);
    for (int mt = 0; mt < 8; ++mt) {
      f32x4 acc = fzero4();
#pragma unroll
      for (int kt = 0; kt < 3; ++kt) acc = mfma16(bw[kt], az[kt][mt], acc);
      st_pk4(&qh[(mt * 16 + l16) * QH_STR + quad * 4],
             (acc[0] + bias[0]) * 0.25f, (acc[1] + bias[1]) * 0.25f,
             (acc[2] + bias[2]) * 0.25f, (acc[3] + bias[3]) * 0.25f);
    }
  }
  __syncthreads();  // all waves done reading sm_A(xo); scratch region free

  bf16x8 bk[8], bv[4];
  // ---- K^T GEMM -> scratch [tok][16] (packed b64), then regs ----
  {
    const int jrow = C_DIM + wv * 16 + l16;
    bf16x8 bw[3];
#pragma unroll
    for (int kt = 0; kt < 3; ++kt)
      bw[kt] = ld8G(w_qkv, isf, (size_t)jrow * C_DIM + kt * 32 + quad * 8);
    float bias[4];
#pragma unroll
    for (int r = 0; r < 4; ++r) bias[r] = ldS(b_qkv, isf, C_DIM + wv * 16 + quad * 4 + r);
    for (int mt = 0; mt < 8; ++mt) {
      f32x4 acc = fzero4();
#pragma unroll
      for (int kt = 0; kt < 3; ++kt) acc = mfma16(bw[kt], az[kt][mt], acc);
      st_pk4(&scr[(mt * 16 + l16) * 16 + quad * 4],
             acc[0] + bias[0], acc[1] + bias[1], acc[2] + bias[2], acc[3] + bias[3]);
    }
    cfence();  // K stores -> bk loads (wave-private, no barrier)
#pragma unroll
    for (int nt = 0; nt < 8; ++nt)
      bk[nt] = (quad < 2) ? ld8(scr + (nt * 16 + l16) * 16 + quad * 8) : zero8();
    cfence();  // bk loads -> V^T stores overwrite K region (WAR)
  }
  // ---- V GEMM (normal) -> scratch V^T [d=l16][tok] stride 136, then regs ----
  {
    const int jcol = 2 * C_DIM + wv * 16 + l16;
    bf16x8 bw[3];
#pragma unroll
    for (int kt = 0; kt < 3; ++kt)
      bw[kt] = ld8G(w_qkv, isf, (size_t)jcol * C_DIM + kt * 32 + quad * 8);
    const float bias = ldS(b_qkv, isf, jcol);
    for (int mt = 0; mt < 8; ++mt) {
      f32x4 acc = fzero4();
#pragma unroll
      for (int kt = 0; kt < 3; ++kt) acc = mfma16(az[kt][mt], bw[kt], acc);
#pragma unroll
      for (int r = 0; r < 4; ++r)
        scr[l16 * VP_STR + (mt * 16 + quad * 4 + r)] = f2bf(acc[r] + bias);
    }
    cfence();  // V^T stores -> bv loads
#pragma unroll
    for (int kt = 0; kt < 4; ++kt)
      bv[kt] = ld8(scr + l16 * VP_STR + kt * 32 + quad * 8);
    cfence();  // bv loads -> P stores overwrite V^T region (WAR)
  }

  // ---- Stage 3: attention, barrier-free; lane-local softmax ----
  {
    const int nu = sm_nu[0] | sm_nu[1];
    for (int qt = 0; qt < 8; ++qt) {
      bf16x8 bq = (quad < 2) ? ld8(qh + (qt * 16 + l16) * QH_STR + quad * 8) : zero8();
      f32x4 s[8];
      __builtin_amdgcn_s_setprio(1);
#pragma unroll
      for (int nt = 0; nt < 8; ++nt) s[nt] = mfma16(bk[nt], bq, fzero4());
      __builtin_amdgcn_s_setprio(0);
      if (nu) {
        const int rc = sm_cls[qt * 16 + l16];
#pragma unroll
        for (int nt = 0; nt < 8; ++nt) {
          int4 cc = *(const int4*)&sm_cls[nt * 16 + quad * 4];
          s[nt][0] += (cc.x != rc) ? -100.0f : 0.0f;
          s[nt][1] += (cc.y != rc) ? -100.0f : 0.0f;
          s[nt][2] += (cc.z != rc) ? -100.0f : 0.0f;
          s[nt][3] += (cc.w != rc) ? -100.0f : 0.0f;
        }
      }
      // softmax over n: 32 in-lane values + cross-quad (2 shfl)
      float m = s[0][0];
#pragma unroll
      for (int nt = 0; nt < 8; ++nt)
#pragma unroll
        for (int r = 0; r < 4; ++r) m = fmaxf(m, s[nt][r]);
      m = fmaxf(m, __shfl_xor(m, 16, 64));
      m = fmaxf(m, __shfl_xor(m, 32, 64));
      float sum = 0.f;
#pragma unroll
      for (int nt = 0; nt < 8; ++nt)
#pragma unroll
        for (int r = 0; r < 4; ++r) {
          float e = __expf(s[nt][r] - m);
          s[nt][r] = e; sum += e;
        }
      sum += __shfl_xor(sum, 16, 64);
      sum += __shfl_xor(sum, 32, 64);
      const float inv = 1.0f / sum;
      cfence();  // previous PV reads done before P overwrite (WAR across iters)
      // P rows [q=l16][n] packed b64 (wave-private scratch)
#pragma unroll
      for (int nt = 0; nt < 8; ++nt)
        st_pk4(&scr[l16 * VP_STR + nt * 16 + quad * 4],
               s[nt][0] * inv, s[nt][1] * inv, s[nt][2] * inv, s[nt][3] * inv);
      cfence();  // P stores -> PV reads (wave-private, no barrier)
      // O^T = V^T * P^T : C col=q(l16), row=d(quad,r)
      f32x4 o = fzero4();
      __builtin_amdgcn_s_setprio(1);
#pragma unroll
      for (int kt = 0; kt < 4; ++kt)
        o = mfma16(bv[kt], ld8(scr + l16 * VP_STR + kt * 32 + quad * 8), o);
      __builtin_amdgcn_s_setprio(0);
      st_pk4(&qh[(qt * 16 + l16) * QH_STR + quad * 4], o[0], o[1], o[2], o[3]);
    }
  }
  __syncthreads();

  // ---- Stage 4: proj + residual + scatter ----
  {
    const int jcol = wv * 16 + l16;
    bf16x8 bp[3];
#pragma unroll
    for (int kt = 0; kt < 3; ++kt)
      bp[kt] = ld8G(w_proj, isf, (size_t)jcol * C_DIM + kt * 32 + quad * 8);
    const float bias = ldS(b_proj, isf, jcol);
    for (int mt = 0; mt < 8; ++mt) {
      f32x4 acc = fzero4();
#pragma unroll
      for (int kt = 0; kt < 3; ++kt) {
        const int c0 = kt * 32 + quad * 8;
        const int h2 = c0 >> 4, off = c0 & 15;
        bf16x8 a = ld8(sm_qB + h2 * QHW + (mt * 16 + l16) * QH_STR + off);
        acc = mfma16(a, bp[kt], acc);
      }
#pragma unroll
      for (int r = 0; r < 4; ++r) {
        int row = mt * 16 + quad * 4 + r;
        size_t addr = (size_t)sm_tok[row] * C_DIM + jcol;
        stO(y, isf, addr, scrub(ldS(x, isf, addr)) + acc[r] + bias);
      }
    }
  }
}

// =====================================================================
// Kernel B: LN2 + fc1 + GELU + fc2 + residual; in place on d_out.
// 128 tok/block, 2048 blocks. Hidden processed in 4 chunks of 96 through
// one reused [128][104] buffer; z A-frags preloaded. LDS ~53KB.
// =====================================================================
__global__ __launch_bounds__(384, 3) void swin_mlp_kernel(
    const void* __restrict__ g2,
    const void* __restrict__ b2,
    const void* __restrict__ w_fc1,
    const void* __restrict__ b_fc1,
    const void* __restrict__ w_fc2,
    const void* __restrict__ b_fc2,
    void* __restrict__ yout,
    const int* __restrict__ flag)
{
  __shared__ __align__(16) unsigned short sm_z[13312];   // [128][104]
  __shared__ __align__(16) unsigned short sm_h[13312];   // [128][104] per chunk (+red alias)
  float* sm_red = (float*)sm_h;

  const int isf = *flag;
  const int tid = threadIdx.x;
  const size_t tok0 = (size_t)blockIdx.x * 128;

  // ---- LN2 ----
  {
    const int n = tid & 127;
    const int part = tid >> 7;
    float v[32];
    if (isf) {
      const float* yp = (const float*)yout + (tok0 + n) * C_DIM + part * 32;
      f32x4 raw[8];
#pragma unroll
      for (int i = 0; i < 8; ++i) raw[i] = ((const f32x4*)yp)[i];
#pragma unroll
      for (int i = 0; i < 32; ++i) v[i] = raw[i >> 2][i & 3];
    } else {
      const unsigned short* yp = (const unsigned short*)yout + (tok0 + n) * C_DIM + part * 32;
      u16x8 raw[4];
#pragma unroll
      for (int i = 0; i < 4; ++i) raw[i] = ((const u16x8*)yp)[i];
#pragma unroll
      for (int i = 0; i < 32; ++i) v[i] = bf2f(raw[i >> 3][i & 7]);
    }
    float s = 0.f, s2 = 0.f;
#pragma unroll
    for (int i = 0; i < 32; ++i) { s += v[i]; s2 += v[i] * v[i]; }
    sm_red[part * 128 + n] = s;
    sm_red[(3 + part) * 128 + n] = s2;
    __syncthreads();
    float tsum = sm_red[0 * 128 + n] + sm_red[1 * 128 + n] + sm_red[2 * 128 + n];
    float tsq  = sm_red[3 * 128 + n] + sm_red[4 * 128 + n] + sm_red[5 * 128 + n];
    float mean = tsum * (1.0f / 96.0f);
    float var = fmaxf(tsq * (1.0f / 96.0f) - mean * mean, 0.0f);
    float rstd = rsqrtf(var + 1e-5f);
    float o[32];
#pragma unroll
    for (int i = 0; i < 32; ++i) {
      int c = part * 32 + i;
      o[i] = (v[i] - mean) * rstd * ldS(g2, isf, c) + ldS(b2, isf, c);
    }
#pragma unroll
    for (int k = 0; k < 4; ++k)
      st_pk8(sm_z + n * XO_STR + part * 32 + k * 8, &o[k * 8]);
  }
  __syncthreads();

  const int wv = tid >> 6;
  const int lane = tid & 63;
  const int quad = lane >> 4;
  const int l16 = lane & 15;
  const int jcol_o = wv * 16 + l16;

  // preload z A-fragments
  bf16x8 az[3][8];
#pragma unroll
  for (int kt = 0; kt < 3; ++kt)
#pragma unroll
    for (int mt = 0; mt < 8; ++mt)
      az[kt][mt] = ld8(sm_z + (mt * 16 + l16) * XO_STR + kt * 32 + quad * 8);

  f32x4 acc2[8];
#pragma unroll
  for (int mt = 0; mt < 8; ++mt) acc2[mt] = fzero4();

  // ---- 4 chunks of 96 hidden dims ----
  for (int c = 0; c < 4; ++c) {
    // fc1 (transposed produce): H^T-tile = W1 * z^T ; packed b64 h-stores
    {
      const int hb = c * 96 + wv * 16;
      bf16x8 bw1[3];
#pragma unroll
      for (int kt = 0; kt < 3; ++kt)
        bw1[kt] = ld8G(w_fc1, isf, (size_t)(hb + l16) * C_DIM + kt * 32 + quad * 8);
      float b1v[4];
#pragma unroll
      for (int r = 0; r < 4; ++r) b1v[r] = ldS(b_fc1, isf, hb + quad * 4 + r);
#pragma unroll
      for (int mt = 0; mt < 8; ++mt) {
        f32x4 acc = fzero4();
#pragma unroll
        for (int kt = 0; kt < 3; ++kt) acc = mfma16(bw1[kt], az[kt][mt], acc);
        float g[4];
#pragma unroll
        for (int r = 0; r < 4; ++r) g[r] = gelu_f(acc[r] + b1v[r]);
        st_pk4(&sm_h[(mt * 16 + l16) * XO_STR + wv * 16 + quad * 4],
               g[0], g[1], g[2], g[3]);
      }
    }
    __syncthreads();
    // fc2 partial over this chunk's 96 k
    {
      bf16x8 bw2[3];
#pragma unroll
      for (int kt = 0; kt < 3; ++kt)
        bw2[kt] = ld8G(w_fc2, isf, (size_t)jcol_o * 384 + c * 96 + kt * 32 + quad * 8);
#pragma unroll
      for (int mt = 0; mt < 8; ++mt) {
#pragma unroll
        for (int kt = 0; kt < 3; ++kt) {
          bf16x8 a = ld8(sm_h + (mt * 16 + l16) * XO_STR + kt * 32 + quad * 8);
          acc2[mt] = mfma16(a, bw2[kt], acc2[mt]);
        }
      }
    }
    if (c < 3) __syncthreads();
  }

  // ---- residual + store ----
  {
    const float bias = ldS(b_fc2, isf, jcol_o);
#pragma unroll
    for (int mt = 0; mt < 8; ++mt) {
#pragma unroll
      for (int r = 0; r < 4; ++r) {
        int row = mt * 16 + quad * 4 + r;
        size_t addr = (tok0 + row) * C_DIM + jcol_o;
        stO(yout, isf, addr, ldS(yout, isf, addr) + acc2[mt][r] + bias);
      }
    }
  }
}

// =====================================================================
extern "C" void kernel_launch(void* const* d_in, const int* in_sizes, int n_in,
                              void* d_out, int out_size, void* d_ws, size_t ws_size,
                              hipStream_t stream) {
  const void* x      = d_in[0];
  // d_in[1] = attn_mask (recomputed analytically; unused)
  const void* g1     = d_in[2];
  const void* b1     = d_in[3];
  const void* w_qkv  = d_in[4];
  const void* b_qkv  = d_in[5];
  const void* w_proj = d_in[6];
  const void* b_proj = d_in[7];
  const void* g2     = d_in[8];
  const void* b2     = d_in[9];
  const void* w_fc1  = d_in[10];
  const void* b_fc1  = d_in[11];
  const void* w_fc2  = d_in[12];
  const void* b_fc2  = d_in[13];
  int* flag = (int*)d_ws;

  dtype_sniff<<<1, 64, 0, stream>>>((const unsigned short*)x, flag);
  swin_attn_kernel<<<2048, 384, 0, stream>>>(x, g1, b1, w_qkv, b_qkv, w_proj, b_proj, d_out, flag);
  swin_mlp_kernel<<<2048, 384, 0, stream>>>(g2, b2, w_fc1, b_fc1, w_fc2, b_fc2, d_out, flag);
}

// Round 4
// 592.365 us; speedup vs baseline: 1.3612x; 1.1735x over previous
//
#include <hip/hip_runtime.h>
#include <math.h>

// ---------- types & helpers ----------
typedef __bf16 bf16x8 __attribute__((ext_vector_type(8)));
typedef unsigned short u16x8 __attribute__((ext_vector_type(8)));
typedef unsigned short u16x4 __attribute__((ext_vector_type(4)));
typedef float f32x4 __attribute__((ext_vector_type(4)));

__device__ __forceinline__ float bf2f(unsigned short u) {
  union { unsigned u; float f; } v; v.u = ((unsigned)u) << 16; return v.f;
}
__device__ __forceinline__ unsigned short f2bf(float f) {
  union { float f; unsigned u; } v; v.f = f;
  unsigned r = v.u + 0x7fffu + ((v.u >> 16) & 1u);
  return (unsigned short)(r >> 16);
}
__device__ __forceinline__ unsigned pk_bf16(float lo, float hi) {
  unsigned r;
  asm("v_cvt_pk_bf16_f32 %0, %1, %2" : "=v"(r) : "v"(lo), "v"(hi));
  return r;
}
// compiler-only memory fence: pins LDS store->load ordering for wave-private
// data exchanged without __syncthreads (DS pipe is in-order per wave).
__device__ __forceinline__ void cfence() { asm volatile("" ::: "memory"); }

__device__ __forceinline__ bf16x8 ld8(const unsigned short* p) {
  return __builtin_bit_cast(bf16x8, *(const u16x8*)p);
}
__device__ __forceinline__ bf16x8 ld8f(const float* p) {
  f32x4 a = *(const f32x4*)p;
  f32x4 b = *(const f32x4*)(p + 4);
  u16x8 u;
#pragma unroll
  for (int i = 0; i < 4; ++i) { u[i] = f2bf(a[i]); u[4 + i] = f2bf(b[i]); }
  return __builtin_bit_cast(bf16x8, u);
}
// dtype-adaptive loads/stores (isf: 1 = buffers are f32, 0 = bf16)
__device__ __forceinline__ float ldS(const void* p, int isf, size_t i) {
  return isf ? ((const float*)p)[i] : bf2f(((const unsigned short*)p)[i]);
}
__device__ __forceinline__ bf16x8 ld8G(const void* p, int isf, size_t i) {
  return isf ? ld8f((const float*)p + i) : ld8((const unsigned short*)p + i);
}
__device__ __forceinline__ void stO(void* p, int isf, size_t i, float v) {
  if (isf) ((float*)p)[i] = v; else ((unsigned short*)p)[i] = f2bf(v);
}
__device__ __forceinline__ bf16x8 zero8() {
  u16x8 z;
#pragma unroll
  for (int i = 0; i < 8; ++i) z[i] = 0;
  return __builtin_bit_cast(bf16x8, z);
}
__device__ __forceinline__ f32x4 fzero4() {
  f32x4 z; z[0] = z[1] = z[2] = z[3] = 0.f; return z;
}
__device__ __forceinline__ f32x4 mfma16(bf16x8 a, bf16x8 b, f32x4 c) {
  return __builtin_amdgcn_mfma_f32_16x16x32_bf16(a, b, c, 0, 0, 0);
}
__device__ __forceinline__ float scrub(float v) {
  return fminf(fmaxf(v, -1e6f), 1e6f);
}
// packed store of 8 bf16 (16B) via ushort-vector (same TBAA class as ld8)
__device__ __forceinline__ void st_pk8(unsigned short* p, const float* v) {
  uint4 w;
  w.x = pk_bf16(v[0], v[1]); w.y = pk_bf16(v[2], v[3]);
  w.z = pk_bf16(v[4], v[5]); w.w = pk_bf16(v[6], v[7]);
  *(u16x8*)p = __builtin_bit_cast(u16x8, w);
}
// packed store of 4 bf16 (8B) via ushort-vector
__device__ __forceinline__ void st_pk4(unsigned short* p, float a, float b, float c, float d) {
  uint2 w; w.x = pk_bf16(a, b); w.y = pk_bf16(c, d);
  *(u16x4*)p = __builtin_bit_cast(u16x4, w);
}
// fast exact-enough GELU: A&S 7.1.26 erf poly, |err(erf)| <= ~1.5e-7
__device__ __forceinline__ float gelu_f(float x) {
  float ax = fabsf(x);
  float t = __builtin_amdgcn_rcpf(1.0f + 0.3275911f * ax);
  float poly = t * (0.254829592f + t * (-0.284496736f + t * (1.421413741f +
               t * (-1.453152027f + t * 1.061405429f))));
  float er = 1.0f - poly * __expf(-ax * ax);
  er = copysignf(er, x);
  return 0.5f * x * (1.0f + er);
}

#define C_DIM 96
#define XO_STR 104   // LN-out row stride (u16)
#define QH_STR 24    // per-head [tok][24] stride (u16): 48B rows, b64/b128 aligned
#define VP_STR 136   // V^T / P row stride (u16): 272B
#define SCRW 2176    // per-wave scratch u16 (max of K-tmp 2048, V^T/P 2176)
#define QHW 3072     // per-head Q/attn-out u16 (128*24)
#define A_HALF 13312 // u16 per half: xo [128][104]
#define QB_HALF 18432// u16 per half: 6x [128][24]

// =====================================================================
// dtype sniffer (unchanged)
__global__ void dtype_sniff(const unsigned short* __restrict__ x, int* __restrict__ flag) {
  int lane = threadIdx.x;  // 64 threads
  int weird = 0;
#pragma unroll
  for (int k = 0; k < 4; ++k) {
    unsigned short w = x[lane * 4 + k];
    int e = (w >> 7) & 0xFF;
    if (e >= 0xC0 || (e != 0 && e <= 0x30)) weird++;
  }
#pragma unroll
  for (int d = 1; d < 64; d <<= 1) weird += __shfl_xor(weird, d, 64);
  if (lane == 0) *flag = (weird > 16) ? 1 : 0;
}

// =====================================================================
// Kernel A: LN1 + shift + window attention + proj + residual -> y
// 1024 blocks x 768 thr (12 waves): TWO windows per block, as two
// independent lockstep halves (waves 0-5 / 6-11). Empirically this
// harness schedules 1 WG/CU regardless of LDS, so resident waves come
// from WG size: 6 -> 12. LDS 129,040 B.
// =====================================================================
__global__ __launch_bounds__(768, 3) void swin_attn_kernel(
    const void* __restrict__ x,
    const void* __restrict__ g1,
    const void* __restrict__ b1,
    const void* __restrict__ w_qkv,
    const void* __restrict__ b_qkv,
    const void* __restrict__ w_proj,
    const void* __restrict__ b_proj,
    void* __restrict__ y,
    const int* __restrict__ flag)
{
  __shared__ __align__(16) unsigned short sm_A[2 * A_HALF];   // per half: xo, later scratch
  __shared__ __align__(16) unsigned short sm_qB[2 * QB_HALF]; // per half: red, later Q/attn-out
  __shared__ int sm_tok[2 * 128];
  __shared__ int sm_cls[2 * 128];
  __shared__ int sm_nu[2][2];

  const int isf = *flag;
  const int tid = threadIdx.x;
  const int half = (tid >= 384) ? 1 : 0;
  const int t = tid - half * 384;          // local tid within half (0..383)
  unsigned short* smA = sm_A + half * A_HALF;
  unsigned short* smQ = sm_qB + half * QB_HALF;
  int* tokp = sm_tok + half * 128;
  int* clsp = sm_cls + half * 128;
  float* sm_red = (float*)smQ;  // 768 floats, dead before Q written

  const int win = blockIdx.x * 2 + half;
  const int b = win >> 10;
  const int rem = win & 1023;
  const int ti = rem >> 8, hi = (rem >> 4) & 15, wi = rem & 15;

  // ---- Stage 1: gather (cyclic shift) + LN1 ----
  {
    const int n = t & 127;
    const int part = t >> 7;
    const int td = n >> 6, hh = (n >> 3) & 7, ww = n & 7;
    const int tt = ti * 2 + td, h = hi * 8 + hh, w = wi * 8 + ww;
    const int ts = (tt + 1) & 7, hs = (h + 4) & 127, ws = (w + 4) & 127;
    const int tok = ((b * 8 + ts) * 128 + hs) * 128 + ws;
    if (part == 0) {
      tokp[n] = tok;
      int ct = (tt < 6) ? 0 : (tt - 5);
      int ch = (h < 120) ? 0 : ((h < 124) ? 1 : 2);
      int cw = (w < 120) ? 0 : ((w < 124) ? 1 : 2);
      int cls = ct * 9 + ch * 3 + cw;
      clsp[n] = cls;
      // window-uniform-class flag (skip mask work on interior windows)
      int t0 = ti * 2;
      int ct0 = (t0 < 6) ? 0 : (t0 - 5);
      int ch0 = (hi < 15) ? 0 : 1;
      int cw0 = (wi < 15) ? 0 : 1;
      int cls0 = ct0 * 9 + ch0 * 3 + cw0;
      unsigned long long bal = __ballot(cls != cls0);
      if ((t & 63) == 0) sm_nu[half][t >> 6] = (bal != 0ULL) ? 1 : 0;
    }
    float v[32];
    if (isf) {
      const float* xp = (const float*)x + (size_t)tok * C_DIM + part * 32;
      f32x4 raw[8];
#pragma unroll
      for (int i = 0; i < 8; ++i) raw[i] = ((const f32x4*)xp)[i];
#pragma unroll
      for (int i = 0; i < 32; ++i) v[i] = raw[i >> 2][i & 3];
    } else {
      const unsigned short* xp = (const unsigned short*)x + (size_t)tok * C_DIM + part * 32;
      u16x8 raw[4];
#pragma unroll
      for (int i = 0; i < 4; ++i) raw[i] = ((const u16x8*)xp)[i];
#pragma unroll
      for (int i = 0; i < 32; ++i) v[i] = bf2f(raw[i >> 3][i & 7]);
    }
    float s = 0.f, s2 = 0.f;
#pragma unroll
    for (int i = 0; i < 32; ++i) {
      v[i] = scrub(v[i]);
      s += v[i]; s2 += v[i] * v[i];
    }
    sm_red[part * 128 + n] = s;
    sm_red[(3 + part) * 128 + n] = s2;
    __syncthreads();
    float tsum = sm_red[0 * 128 + n] + sm_red[1 * 128 + n] + sm_red[2 * 128 + n];
    float tsq  = sm_red[3 * 128 + n] + sm_red[4 * 128 + n] + sm_red[5 * 128 + n];
    float mean = tsum * (1.0f / 96.0f);
    float var = fmaxf(tsq * (1.0f / 96.0f) - mean * mean, 0.0f);
    float rstd = rsqrtf(var + 1e-5f);
    float o[32];
#pragma unroll
    for (int i = 0; i < 32; ++i) {
      int c = part * 32 + i;
      o[i] = (v[i] - mean) * rstd * ldS(g1, isf, c) + ldS(b1, isf, c);
    }
#pragma unroll
    for (int k = 0; k < 4; ++k)
      st_pk8(smA + n * XO_STR + part * 32 + k * 8, &o[k * 8]);
  }
  __syncthreads();

  const int wv = t >> 6;            // head 0..5 within half
  const int lane = t & 63;
  const int quad = lane >> 4;
  const int l16 = lane & 15;
  unsigned short* scr = smA + wv * SCRW;
  unsigned short* qh  = smQ + wv * QHW;

  // ---- preload A-fragments of LN-out (xw): row=tok on l16, k=c on quad ----
  bf16x8 az[3][8];
#pragma unroll
  for (int kt = 0; kt < 3; ++kt)
#pragma unroll
    for (int mt = 0; mt < 8; ++mt)
      az[kt][mt] = ld8(smA + (mt * 16 + l16) * XO_STR + kt * 32 + quad * 8);

  // ---- hoisted weight loads for Q, K, V (hide global latency under Q GEMM) ----
  bf16x8 bwQ[3], bwK[3], bwV[3];
  {
    const int jq = wv * 16 + l16;
#pragma unroll
    for (int kt = 0; kt < 3; ++kt) {
      bwQ[kt] = ld8G(w_qkv, isf, (size_t)jq * C_DIM + kt * 32 + quad * 8);
      bwK[kt] = ld8G(w_qkv, isf, (size_t)(C_DIM + jq) * C_DIM + kt * 32 + quad * 8);
      bwV[kt] = ld8G(w_qkv, isf, (size_t)(2 * C_DIM + jq) * C_DIM + kt * 32 + quad * 8);
    }
  }

  // ---- Q^T GEMM: C col=tok(l16), row=d(quad,r); packed b64 ----
  {
    float bias[4];
#pragma unroll
    for (int r = 0; r < 4; ++r) bias[r] = ldS(b_qkv, isf, wv * 16 + quad * 4 + r);
    for (int mt = 0; mt < 8; ++mt) {
      f32x4 acc = fzero4();
#pragma unroll
      for (int kt = 0; kt < 3; ++kt) acc = mfma16(bwQ[kt], az[kt][mt], acc);
      st_pk4(&qh[(mt * 16 + l16) * QH_STR + quad * 4],
             (acc[0] + bias[0]) * 0.25f, (acc[1] + bias[1]) * 0.25f,
             (acc[2] + bias[2]) * 0.25f, (acc[3] + bias[3]) * 0.25f);
    }
  }
  __syncthreads();  // all waves done reading smA(xo); scratch region free

  bf16x8 bk[8], bv[4];
  // ---- K^T GEMM -> scratch [tok][16] (packed b64), then regs ----
  {
    float bias[4];
#pragma unroll
    for (int r = 0; r < 4; ++r) bias[r] = ldS(b_qkv, isf, C_DIM + wv * 16 + quad * 4 + r);
    for (int mt = 0; mt < 8; ++mt) {
      f32x4 acc = fzero4();
#pragma unroll
      for (int kt = 0; kt < 3; ++kt) acc = mfma16(bwK[kt], az[kt][mt], acc);
      st_pk4(&scr[(mt * 16 + l16) * 16 + quad * 4],
             acc[0] + bias[0], acc[1] + bias[1], acc[2] + bias[2], acc[3] + bias[3]);
    }
    cfence();  // K stores -> bk loads (wave-private, no barrier)
#pragma unroll
    for (int nt = 0; nt < 8; ++nt)
      bk[nt] = (quad < 2) ? ld8(scr + (nt * 16 + l16) * 16 + quad * 8) : zero8();
    cfence();  // bk loads -> V^T stores overwrite K region (WAR)
  }
  // ---- V GEMM (normal) -> scratch V^T [d=l16][tok] stride 136, then regs ----
  {
    const float bias = ldS(b_qkv, isf, 2 * C_DIM + wv * 16 + l16);
    for (int mt = 0; mt < 8; ++mt) {
      f32x4 acc = fzero4();
#pragma unroll
      for (int kt = 0; kt < 3; ++kt) acc = mfma16(az[kt][mt], bwV[kt], acc);
#pragma unroll
      for (int r = 0; r < 4; ++r)
        scr[l16 * VP_STR + (mt * 16 + quad * 4 + r)] = f2bf(acc[r] + bias);
    }
    cfence();  // V^T stores -> bv loads
#pragma unroll
    for (int kt = 0; kt < 4; ++kt)
      bv[kt] = ld8(scr + l16 * VP_STR + kt * 32 + quad * 8);
    cfence();  // bv loads -> P stores overwrite V^T region (WAR)
  }

  // ---- hoisted proj weights (hide under attention) ----
  bf16x8 bp[3];
  {
    const int jcol = wv * 16 + l16;
#pragma unroll
    for (int kt = 0; kt < 3; ++kt)
      bp[kt] = ld8G(w_proj, isf, (size_t)jcol * C_DIM + kt * 32 + quad * 8);
  }

  // ---- Stage 3: attention, barrier-free; lane-local softmax ----
  {
    const int nu = sm_nu[half][0] | sm_nu[half][1];
    for (int qt = 0; qt < 8; ++qt) {
      bf16x8 bq = (quad < 2) ? ld8(qh + (qt * 16 + l16) * QH_STR + quad * 8) : zero8();
      f32x4 s[8];
      __builtin_amdgcn_s_setprio(1);
#pragma unroll
      for (int nt = 0; nt < 8; ++nt) s[nt] = mfma16(bk[nt], bq, fzero4());
      __builtin_amdgcn_s_setprio(0);
      if (nu) {
        const int rc = clsp[qt * 16 + l16];
#pragma unroll
        for (int nt = 0; nt < 8; ++nt) {
          int4 cc = *(const int4*)&clsp[nt * 16 + quad * 4];
          s[nt][0] += (cc.x != rc) ? -100.0f : 0.0f;
          s[nt][1] += (cc.y != rc) ? -100.0f : 0.0f;
          s[nt][2] += (cc.z != rc) ? -100.0f : 0.0f;
          s[nt][3] += (cc.w != rc) ? -100.0f : 0.0f;
        }
      }
      // softmax over n: 32 in-lane values + cross-quad (2 shfl)
      float m = s[0][0];
#pragma unroll
      for (int nt = 0; nt < 8; ++nt)
#pragma unroll
        for (int r = 0; r < 4; ++r) m = fmaxf(m, s[nt][r]);
      m = fmaxf(m, __shfl_xor(m, 16, 64));
      m = fmaxf(m, __shfl_xor(m, 32, 64));
      float sum = 0.f;
#pragma unroll
      for (int nt = 0; nt < 8; ++nt)
#pragma unroll
        for (int r = 0; r < 4; ++r) {
          float e = __expf(s[nt][r] - m);
          s[nt][r] = e; sum += e;
        }
      sum += __shfl_xor(sum, 16, 64);
      sum += __shfl_xor(sum, 32, 64);
      const float inv = 1.0f / sum;
      cfence();  // previous PV reads done before P overwrite (WAR across iters)
      // P rows [q=l16][n] packed b64 (wave-private scratch)
#pragma unroll
      for (int nt = 0; nt < 8; ++nt)
        st_pk4(&scr[l16 * VP_STR + nt * 16 + quad * 4],
               s[nt][0] * inv, s[nt][1] * inv, s[nt][2] * inv, s[nt][3] * inv);
      cfence();  // P stores -> PV reads (wave-private, no barrier)
      // O^T = V^T * P^T : C col=q(l16), row=d(quad,r)
      f32x4 o = fzero4();
      __builtin_amdgcn_s_setprio(1);
#pragma unroll
      for (int kt = 0; kt < 4; ++kt)
        o = mfma16(bv[kt], ld8(scr + l16 * VP_STR + kt * 32 + quad * 8), o);
      __builtin_amdgcn_s_setprio(0);
      st_pk4(&qh[(qt * 16 + l16) * QH_STR + quad * 4], o[0], o[1], o[2], o[3]);
    }
  }
  __syncthreads();

  // ---- Stage 4: proj + residual + scatter ----
  {
    const int jcol = wv * 16 + l16;
    const float bias = ldS(b_proj, isf, jcol);
    for (int mt = 0; mt < 8; ++mt) {
      f32x4 acc = fzero4();
#pragma unroll
      for (int kt = 0; kt < 3; ++kt) {
        const int c0 = kt * 32 + quad * 8;
        const int h2 = c0 >> 4, off = c0 & 15;
        bf16x8 a = ld8(smQ + h2 * QHW + (mt * 16 + l16) * QH_STR + off);
        acc = mfma16(a, bp[kt], acc);
      }
#pragma unroll
      for (int r = 0; r < 4; ++r) {
        int row = mt * 16 + quad * 4 + r;
        size_t addr = (size_t)tokp[row] * C_DIM + jcol;
        stO(y, isf, addr, scrub(ldS(x, isf, addr)) + acc[r] + bias);
      }
    }
  }
}

// =====================================================================
// Kernel B: LN2 + fc1 + GELU + fc2 + residual; in place on d_out.
// 1024 blocks x 768 thr: 256 tokens/block as two lockstep halves of
// 128 tokens x 6 waves. LDS 106,496 B. fc2 weights prefetched at chunk
// top to hide L2 latency under fc1+GELU.
// =====================================================================
__global__ __launch_bounds__(768, 3) void swin_mlp_kernel(
    const void* __restrict__ g2,
    const void* __restrict__ b2,
    const void* __restrict__ w_fc1,
    const void* __restrict__ b_fc1,
    const void* __restrict__ w_fc2,
    const void* __restrict__ b_fc2,
    void* __restrict__ yout,
    const int* __restrict__ flag)
{
  __shared__ __align__(16) unsigned short sm_z[2 * A_HALF];   // per half [128][104]
  __shared__ __align__(16) unsigned short sm_h[2 * A_HALF];   // per half [128][104] (+red alias)

  const int isf = *flag;
  const int tid = threadIdx.x;
  const int half = (tid >= 384) ? 1 : 0;
  const int t = tid - half * 384;
  unsigned short* smz = sm_z + half * A_HALF;
  unsigned short* smh = sm_h + half * A_HALF;
  float* sm_red = (float*)smh;
  const size_t tok0 = ((size_t)blockIdx.x * 2 + half) * 128;

  // ---- LN2 ----
  {
    const int n = t & 127;
    const int part = t >> 7;
    float v[32];
    if (isf) {
      const float* yp = (const float*)yout + (tok0 + n) * C_DIM + part * 32;
      f32x4 raw[8];
#pragma unroll
      for (int i = 0; i < 8; ++i) raw[i] = ((const f32x4*)yp)[i];
#pragma unroll
      for (int i = 0; i < 32; ++i) v[i] = raw[i >> 2][i & 3];
    } else {
      const unsigned short* yp = (const unsigned short*)yout + (tok0 + n) * C_DIM + part * 32;
      u16x8 raw[4];
#pragma unroll
      for (int i = 0; i < 4; ++i) raw[i] = ((const u16x8*)yp)[i];
#pragma unroll
      for (int i = 0; i < 32; ++i) v[i] = bf2f(raw[i >> 3][i & 7]);
    }
    float s = 0.f, s2 = 0.f;
#pragma unroll
    for (int i = 0; i < 32; ++i) { s += v[i]; s2 += v[i] * v[i]; }
    sm_red[part * 128 + n] = s;
    sm_red[(3 + part) * 128 + n] = s2;
    __syncthreads();
    float tsum = sm_red[0 * 128 + n] + sm_red[1 * 128 + n] + sm_red[2 * 128 + n];
    float tsq  = sm_red[3 * 128 + n] + sm_red[4 * 128 + n] + sm_red[5 * 128 + n];
    float mean = tsum * (1.0f / 96.0f);
    float var = fmaxf(tsq * (1.0f / 96.0f) - mean * mean, 0.0f);
    float rstd = rsqrtf(var + 1e-5f);
    float o[32];
#pragma unroll
    for (int i = 0; i < 32; ++i) {
      int c = part * 32 + i;
      o[i] = (v[i] - mean) * rstd * ldS(g2, isf, c) + ldS(b2, isf, c);
    }
#pragma unroll
    for (int k = 0; k < 4; ++k)
      st_pk8(smz + n * XO_STR + part * 32 + k * 8, &o[k * 8]);
  }
  __syncthreads();

  const int wv = t >> 6;
  const int lane = t & 63;
  const int quad = lane >> 4;
  const int l16 = lane & 15;
  const int jcol_o = wv * 16 + l16;

  // preload z A-fragments
  bf16x8 az[3][8];
#pragma unroll
  for (int kt = 0; kt < 3; ++kt)
#pragma unroll
    for (int mt = 0; mt < 8; ++mt)
      az[kt][mt] = ld8(smz + (mt * 16 + l16) * XO_STR + kt * 32 + quad * 8);

  f32x4 acc2[8];
#pragma unroll
  for (int mt = 0; mt < 8; ++mt) acc2[mt] = fzero4();

  // ---- 4 chunks of 96 hidden dims ----
  for (int c = 0; c < 4; ++c) {
    // prefetch BOTH weight sets for this chunk up front
    const int hb = c * 96 + wv * 16;
    bf16x8 bw1[3], bw2[3];
#pragma unroll
    for (int kt = 0; kt < 3; ++kt) {
      bw1[kt] = ld8G(w_fc1, isf, (size_t)(hb + l16) * C_DIM + kt * 32 + quad * 8);
      bw2[kt] = ld8G(w_fc2, isf, (size_t)jcol_o * 384 + c * 96 + kt * 32 + quad * 8);
    }
    float b1v[4];
#pragma unroll
    for (int r = 0; r < 4; ++r) b1v[r] = ldS(b_fc1, isf, hb + quad * 4 + r);
    // fc1 (transposed produce): H^T-tile = W1 * z^T ; packed b64 h-stores
#pragma unroll
    for (int mt = 0; mt < 8; ++mt) {
      f32x4 acc = fzero4();
#pragma unroll
      for (int kt = 0; kt < 3; ++kt) acc = mfma16(bw1[kt], az[kt][mt], acc);
      float g[4];
#pragma unroll
      for (int r = 0; r < 4; ++r) g[r] = gelu_f(acc[r] + b1v[r]);
      st_pk4(&smh[(mt * 16 + l16) * XO_STR + wv * 16 + quad * 4],
             g[0], g[1], g[2], g[3]);
    }
    __syncthreads();
    // fc2 partial over this chunk's 96 k
#pragma unroll
    for (int mt = 0; mt < 8; ++mt) {
#pragma unroll
      for (int kt = 0; kt < 3; ++kt) {
        bf16x8 a = ld8(smh + (mt * 16 + l16) * XO_STR + kt * 32 + quad * 8);
        acc2[mt] = mfma16(a, bw2[kt], acc2[mt]);
      }
    }
    if (c < 3) __syncthreads();
  }

  // ---- residual + store ----
  {
    const float bias = ldS(b_fc2, isf, jcol_o);
#pragma unroll
    for (int mt = 0; mt < 8; ++mt) {
#pragma unroll
      for (int r = 0; r < 4; ++r) {
        int row = mt * 16 + quad * 4 + r;
        size_t addr = (tok0 + row) * C_DIM + jcol_o;
        stO(yout, isf, addr, ldS(yout, isf, addr) + acc2[mt][r] + bias);
      }
    }
  }
}

// =====================================================================
extern "C" void kernel_launch(void* const* d_in, const int* in_sizes, int n_in,
                              void* d_out, int out_size, void* d_ws, size_t ws_size,
                              hipStream_t stream) {
  const void* x      = d_in[0];
  // d_in[1] = attn_mask (recomputed analytically; unused)
  const void* g1     = d_in[2];
  const void* b1     = d_in[3];
  const void* w_qkv  = d_in[4];
  const void* b_qkv  = d_in[5];
  const void* w_proj = d_in[6];
  const void* b_proj = d_in[7];
  const void* g2     = d_in[8];
  const void* b2     = d_in[9];
  const void* w_fc1  = d_in[10];
  const void* b_fc1  = d_in[11];
  const void* w_fc2  = d_in[12];
  const void* b_fc2  = d_in[13];
  int* flag = (int*)d_ws;

  dtype_sniff<<<1, 64, 0, stream>>>((const unsigned short*)x, flag);
  swin_attn_kernel<<<1024, 768, 0, stream>>>(x, g1, b1, w_qkv, b_qkv, w_proj, b_proj, d_out, flag);
  swin_mlp_kernel<<<1024, 768, 0, stream>>>(g2, b2, w_fc1, b_fc1, w_fc2, b_fc2, d_out, flag);
}

// Round 5
// 506.374 us; speedup vs baseline: 1.5923x; 1.1698x over previous
//
#include <hip/hip_runtime.h>
#include <math.h>

// ---------- types & helpers ----------
typedef __bf16 bf16x8 __attribute__((ext_vector_type(8)));
typedef unsigned short u16x8 __attribute__((ext_vector_type(8)));
typedef unsigned short u16x4 __attribute__((ext_vector_type(4)));
typedef float f32x4 __attribute__((ext_vector_type(4)));

__device__ __forceinline__ float bf2f(unsigned short u) {
  union { unsigned u; float f; } v; v.u = ((unsigned)u) << 16; return v.f;
}
__device__ __forceinline__ unsigned short f2bf(float f) {
  union { float f; unsigned u; } v; v.f = f;
  unsigned r = v.u + 0x7fffu + ((v.u >> 16) & 1u);
  return (unsigned short)(r >> 16);
}
__device__ __forceinline__ unsigned pk_bf16(float lo, float hi) {
  unsigned r;
  asm("v_cvt_pk_bf16_f32 %0, %1, %2" : "=v"(r) : "v"(lo), "v"(hi));
  return r;
}
// compiler-only memory fence: pins LDS store->load ordering for wave-private
// data exchanged without __syncthreads (DS pipe is in-order per wave).
__device__ __forceinline__ void cfence() { asm volatile("" ::: "memory"); }

__device__ __forceinline__ bf16x8 ld8(const unsigned short* p) {
  return __builtin_bit_cast(bf16x8, *(const u16x8*)p);
}
__device__ __forceinline__ bf16x8 ld8f(const float* p) {
  f32x4 a = *(const f32x4*)p;
  f32x4 b = *(const f32x4*)(p + 4);
  u16x8 u;
#pragma unroll
  for (int i = 0; i < 4; ++i) { u[i] = f2bf(a[i]); u[4 + i] = f2bf(b[i]); }
  return __builtin_bit_cast(bf16x8, u);
}
// dtype-adaptive loads/stores (isf: 1 = buffers are f32, 0 = bf16)
__device__ __forceinline__ float ldS(const void* p, int isf, size_t i) {
  return isf ? ((const float*)p)[i] : bf2f(((const unsigned short*)p)[i]);
}
__device__ __forceinline__ bf16x8 ld8G(const void* p, int isf, size_t i) {
  return isf ? ld8f((const float*)p + i) : ld8((const unsigned short*)p + i);
}
__device__ __forceinline__ bf16x8 zero8() {
  u16x8 z;
#pragma unroll
  for (int i = 0; i < 8; ++i) z[i] = 0;
  return __builtin_bit_cast(bf16x8, z);
}
__device__ __forceinline__ f32x4 fzero4() {
  f32x4 z; z[0] = z[1] = z[2] = z[3] = 0.f; return z;
}
__device__ __forceinline__ f32x4 mfma16(bf16x8 a, bf16x8 b, f32x4 c) {
  return __builtin_amdgcn_mfma_f32_16x16x32_bf16(a, b, c, 0, 0, 0);
}
__device__ __forceinline__ float scrub(float v) {
  return fminf(fmaxf(v, -1e6f), 1e6f);
}
// packed store of 8 bf16 (16B) via ushort-vector (same TBAA class as ld8)
__device__ __forceinline__ void st_pk8(unsigned short* p, const float* v) {
  uint4 w;
  w.x = pk_bf16(v[0], v[1]); w.y = pk_bf16(v[2], v[3]);
  w.z = pk_bf16(v[4], v[5]); w.w = pk_bf16(v[6], v[7]);
  *(u16x8*)p = __builtin_bit_cast(u16x8, w);
}
// packed store of 4 bf16 (8B) via ushort-vector
__device__ __forceinline__ void st_pk4(unsigned short* p, float a, float b, float c, float d) {
  uint2 w; w.x = pk_bf16(a, b); w.y = pk_bf16(c, d);
  *(u16x4*)p = __builtin_bit_cast(u16x4, w);
}
// fast exact-enough GELU: A&S 7.1.26 erf poly, |err(erf)| <= ~1.5e-7
__device__ __forceinline__ float gelu_f(float x) {
  float ax = fabsf(x);
  float t = __builtin_amdgcn_rcpf(1.0f + 0.3275911f * ax);
  float poly = t * (0.254829592f + t * (-0.284496736f + t * (1.421413741f +
               t * (-1.453152027f + t * 1.061405429f))));
  float er = 1.0f - poly * __expf(-ax * ax);
  er = copysignf(er, x);
  return 0.5f * x * (1.0f + er);
}

#define C_DIM 96
#define XO_STR 104   // LN-out / z / h row stride (u16)
#define QH_STR 24    // per-head [tok][24] stride (u16)
#define VP_STR 136   // V^T / P row stride (u16): 272B
#define SCRW 2176    // per-wave scratch u16
#define QHW 3072     // per-head Q/attn-out u16 (128*24)
#define A_HALF 13312 // u16 per half: xo/z [128][104]
#define QB_HALF 18432// u16 per half: 6x [128][24]; phase B: h + red + mr

// =====================================================================
// dtype sniffer (unchanged)
__global__ void dtype_sniff(const unsigned short* __restrict__ x, int* __restrict__ flag) {
  int lane = threadIdx.x;  // 64 threads
  int weird = 0;
#pragma unroll
  for (int k = 0; k < 4; ++k) {
    unsigned short w = x[lane * 4 + k];
    int e = (w >> 7) & 0xFF;
    if (e >= 0xC0 || (e != 0 && e <= 0x30)) weird++;
  }
#pragma unroll
  for (int d = 1; d < 64; d <<= 1) weird += __shfl_xor(weird, d, 64);
  if (lane == 0) *flag = (weird > 16) ? 1 : 0;
}

// =====================================================================
// FUSED kernel: LN1 + shift + window attention + proj + residual (y in
// VGPRs) + LN2 + fc1 + GELU + fc2 + residual -> out. No global y
// round-trip. 1024 blocks x 768 thr (12 waves): two windows per block
// as two lockstep halves (waves 0-5 / 6-11). LDS 129,040 B.
// =====================================================================
__global__ __launch_bounds__(768, 3) void swin_block_kernel(
    const void* __restrict__ x,
    const void* __restrict__ g1,
    const void* __restrict__ b1,
    const void* __restrict__ w_qkv,
    const void* __restrict__ b_qkv,
    const void* __restrict__ w_proj,
    const void* __restrict__ b_proj,
    const void* __restrict__ g2,
    const void* __restrict__ b2,
    const void* __restrict__ w_fc1,
    const void* __restrict__ b_fc1,
    const void* __restrict__ w_fc2,
    const void* __restrict__ b_fc2,
    void* __restrict__ y,
    const int* __restrict__ flag)
{
  __shared__ __align__(16) unsigned short sm_A[2 * A_HALF];   // xo -> scratch -> z
  __shared__ __align__(16) unsigned short sm_qB[2 * QB_HALF]; // red -> Q/attn-out -> h+red2+mr
  __shared__ int sm_tok[2 * 128];
  __shared__ int sm_cls[2 * 128];
  __shared__ int sm_nu[2][2];

  const int isf = *flag;
  const int tid = threadIdx.x;
  const int half = (tid >= 384) ? 1 : 0;
  const int t = tid - half * 384;          // local tid within half (0..383)
  unsigned short* smA = sm_A + half * A_HALF;
  unsigned short* smQ = sm_qB + half * QB_HALF;
  int* tokp = sm_tok + half * 128;
  int* clsp = sm_cls + half * 128;
  float* sm_red = (float*)smQ;  // 768 floats, dead before Q written

  const int win = blockIdx.x * 2 + half;
  const int b = win >> 10;
  const int rem = win & 1023;
  const int ti = rem >> 8, hi = (rem >> 4) & 15, wi = rem & 15;

  // ---- Stage 1: gather (cyclic shift) + LN1 ----
  {
    const int n = t & 127;
    const int part = t >> 7;
    const int td = n >> 6, hh = (n >> 3) & 7, ww = n & 7;
    const int tt = ti * 2 + td, h = hi * 8 + hh, w = wi * 8 + ww;
    const int ts = (tt + 1) & 7, hs = (h + 4) & 127, ws = (w + 4) & 127;
    const int tok = ((b * 8 + ts) * 128 + hs) * 128 + ws;
    if (part == 0) {
      tokp[n] = tok;
      int ct = (tt < 6) ? 0 : (tt - 5);
      int ch = (h < 120) ? 0 : ((h < 124) ? 1 : 2);
      int cw = (w < 120) ? 0 : ((w < 124) ? 1 : 2);
      int cls = ct * 9 + ch * 3 + cw;
      clsp[n] = cls;
      int t0 = ti * 2;
      int ct0 = (t0 < 6) ? 0 : (t0 - 5);
      int ch0 = (hi < 15) ? 0 : 1;
      int cw0 = (wi < 15) ? 0 : 1;
      int cls0 = ct0 * 9 + ch0 * 3 + cw0;
      unsigned long long bal = __ballot(cls != cls0);
      if ((t & 63) == 0) sm_nu[half][t >> 6] = (bal != 0ULL) ? 1 : 0;
    }
    float v[32];
    if (isf) {
      const float* xp = (const float*)x + (size_t)tok * C_DIM + part * 32;
      f32x4 raw[8];
#pragma unroll
      for (int i = 0; i < 8; ++i) raw[i] = ((const f32x4*)xp)[i];
#pragma unroll
      for (int i = 0; i < 32; ++i) v[i] = raw[i >> 2][i & 3];
    } else {
      const unsigned short* xp = (const unsigned short*)x + (size_t)tok * C_DIM + part * 32;
      u16x8 raw[4];
#pragma unroll
      for (int i = 0; i < 4; ++i) raw[i] = ((const u16x8*)xp)[i];
#pragma unroll
      for (int i = 0; i < 32; ++i) v[i] = bf2f(raw[i >> 3][i & 7]);
    }
    float s = 0.f, s2 = 0.f;
#pragma unroll
    for (int i = 0; i < 32; ++i) {
      v[i] = scrub(v[i]);
      s += v[i]; s2 += v[i] * v[i];
    }
    sm_red[part * 128 + n] = s;
    sm_red[(3 + part) * 128 + n] = s2;
    __syncthreads();
    float tsum = sm_red[0 * 128 + n] + sm_red[1 * 128 + n] + sm_red[2 * 128 + n];
    float tsq  = sm_red[3 * 128 + n] + sm_red[4 * 128 + n] + sm_red[5 * 128 + n];
    float mean = tsum * (1.0f / 96.0f);
    float var = fmaxf(tsq * (1.0f / 96.0f) - mean * mean, 0.0f);
    float rstd = rsqrtf(var + 1e-5f);
    float o[32];
#pragma unroll
    for (int i = 0; i < 32; ++i) {
      int c = part * 32 + i;
      o[i] = (v[i] - mean) * rstd * ldS(g1, isf, c) + ldS(b1, isf, c);
    }
#pragma unroll
    for (int k = 0; k < 4; ++k)
      st_pk8(smA + n * XO_STR + part * 32 + k * 8, &o[k * 8]);
  }
  __syncthreads();

  const int wv = t >> 6;            // head 0..5 within half
  const int lane = t & 63;
  const int quad = lane >> 4;
  const int l16 = lane & 15;
  unsigned short* scr = smA + wv * SCRW;
  unsigned short* qh  = smQ + wv * QHW;

  // ---- preload A-fragments of LN-out (xw): row=tok on l16, k=c on quad ----
  bf16x8 az[3][8];
#pragma unroll
  for (int kt = 0; kt < 3; ++kt)
#pragma unroll
    for (int mt = 0; mt < 8; ++mt)
      az[kt][mt] = ld8(smA + (mt * 16 + l16) * XO_STR + kt * 32 + quad * 8);

  // ---- hoisted weight loads for Q, K, V ----
  bf16x8 bwQ[3], bwK[3], bwV[3];
  {
    const int jq = wv * 16 + l16;
#pragma unroll
    for (int kt = 0; kt < 3; ++kt) {
      bwQ[kt] = ld8G(w_qkv, isf, (size_t)jq * C_DIM + kt * 32 + quad * 8);
      bwK[kt] = ld8G(w_qkv, isf, (size_t)(C_DIM + jq) * C_DIM + kt * 32 + quad * 8);
      bwV[kt] = ld8G(w_qkv, isf, (size_t)(2 * C_DIM + jq) * C_DIM + kt * 32 + quad * 8);
    }
  }

  // ---- Q^T GEMM: C col=tok(l16), row=d(quad,r); packed b64 ----
  {
    float bias[4];
#pragma unroll
    for (int r = 0; r < 4; ++r) bias[r] = ldS(b_qkv, isf, wv * 16 + quad * 4 + r);
    for (int mt = 0; mt < 8; ++mt) {
      f32x4 acc = fzero4();
#pragma unroll
      for (int kt = 0; kt < 3; ++kt) acc = mfma16(bwQ[kt], az[kt][mt], acc);
      st_pk4(&qh[(mt * 16 + l16) * QH_STR + quad * 4],
             (acc[0] + bias[0]) * 0.25f, (acc[1] + bias[1]) * 0.25f,
             (acc[2] + bias[2]) * 0.25f, (acc[3] + bias[3]) * 0.25f);
    }
  }
  __syncthreads();  // all waves done reading smA(xo); scratch region free

  bf16x8 bk[8], bv[4];
  // ---- K^T GEMM -> scratch [tok][16] (packed b64), then regs ----
  {
    float bias[4];
#pragma unroll
    for (int r = 0; r < 4; ++r) bias[r] = ldS(b_qkv, isf, C_DIM + wv * 16 + quad * 4 + r);
    for (int mt = 0; mt < 8; ++mt) {
      f32x4 acc = fzero4();
#pragma unroll
      for (int kt = 0; kt < 3; ++kt) acc = mfma16(bwK[kt], az[kt][mt], acc);
      st_pk4(&scr[(mt * 16 + l16) * 16 + quad * 4],
             acc[0] + bias[0], acc[1] + bias[1], acc[2] + bias[2], acc[3] + bias[3]);
    }
    cfence();  // K stores -> bk loads (wave-private, no barrier)
#pragma unroll
    for (int nt = 0; nt < 8; ++nt)
      bk[nt] = (quad < 2) ? ld8(scr + (nt * 16 + l16) * 16 + quad * 8) : zero8();
    cfence();  // bk loads -> V^T stores overwrite K region (WAR)
  }
  // ---- V GEMM (normal) -> scratch V^T [d=l16][tok] stride 136, then regs ----
  {
    const float bias = ldS(b_qkv, isf, 2 * C_DIM + wv * 16 + l16);
    for (int mt = 0; mt < 8; ++mt) {
      f32x4 acc = fzero4();
#pragma unroll
      for (int kt = 0; kt < 3; ++kt) acc = mfma16(az[kt][mt], bwV[kt], acc);
#pragma unroll
      for (int r = 0; r < 4; ++r)
        scr[l16 * VP_STR + (mt * 16 + quad * 4 + r)] = f2bf(acc[r] + bias);
    }
    cfence();  // V^T stores -> bv loads
#pragma unroll
    for (int kt = 0; kt < 4; ++kt)
      bv[kt] = ld8(scr + l16 * VP_STR + kt * 32 + quad * 8);
    cfence();  // bv loads -> P stores overwrite V^T region (WAR)
  }

  // ---- hoisted proj weights (A-role: w_proj[och=wv*16+l16][k]) ----
  bf16x8 bp[3];
  {
    const int jcol = wv * 16 + l16;
#pragma unroll
    for (int kt = 0; kt < 3; ++kt)
      bp[kt] = ld8G(w_proj, isf, (size_t)jcol * C_DIM + kt * 32 + quad * 8);
  }

  // ---- Stage 3: attention, barrier-free; lane-local softmax ----
  {
    const int nu = sm_nu[half][0] | sm_nu[half][1];
    for (int qt = 0; qt < 8; ++qt) {
      bf16x8 bq = (quad < 2) ? ld8(qh + (qt * 16 + l16) * QH_STR + quad * 8) : zero8();
      f32x4 s[8];
      __builtin_amdgcn_s_setprio(1);
#pragma unroll
      for (int nt = 0; nt < 8; ++nt) s[nt] = mfma16(bk[nt], bq, fzero4());
      __builtin_amdgcn_s_setprio(0);
      if (nu) {
        const int rc = clsp[qt * 16 + l16];
#pragma unroll
        for (int nt = 0; nt < 8; ++nt) {
          int4 cc = *(const int4*)&clsp[nt * 16 + quad * 4];
          s[nt][0] += (cc.x != rc) ? -100.0f : 0.0f;
          s[nt][1] += (cc.y != rc) ? -100.0f : 0.0f;
          s[nt][2] += (cc.z != rc) ? -100.0f : 0.0f;
          s[nt][3] += (cc.w != rc) ? -100.0f : 0.0f;
        }
      }
      float m = s[0][0];
#pragma unroll
      for (int nt = 0; nt < 8; ++nt)
#pragma unroll
        for (int r = 0; r < 4; ++r) m = fmaxf(m, s[nt][r]);
      m = fmaxf(m, __shfl_xor(m, 16, 64));
      m = fmaxf(m, __shfl_xor(m, 32, 64));
      float sum = 0.f;
#pragma unroll
      for (int nt = 0; nt < 8; ++nt)
#pragma unroll
        for (int r = 0; r < 4; ++r) {
          float e = __expf(s[nt][r] - m);
          s[nt][r] = e; sum += e;
        }
      sum += __shfl_xor(sum, 16, 64);
      sum += __shfl_xor(sum, 32, 64);
      const float inv = 1.0f / sum;
      cfence();  // previous PV reads done before P overwrite (WAR across iters)
#pragma unroll
      for (int nt = 0; nt < 8; ++nt)
        st_pk4(&scr[l16 * VP_STR + nt * 16 + quad * 4],
               s[nt][0] * inv, s[nt][1] * inv, s[nt][2] * inv, s[nt][3] * inv);
      cfence();  // P stores -> PV reads (wave-private, no barrier)
      f32x4 o = fzero4();
      __builtin_amdgcn_s_setprio(1);
#pragma unroll
      for (int kt = 0; kt < 4; ++kt)
        o = mfma16(bv[kt], ld8(scr + l16 * VP_STR + kt * 32 + quad * 8), o);
      __builtin_amdgcn_s_setprio(0);
      st_pk4(&qh[(qt * 16 + l16) * QH_STR + quad * 4], o[0], o[1], o[2], o[3]);
    }
  }
  __syncthreads();

  // ---- Stage 4': proj (transposed produce) + residual -> y' in VGPRs ----
  // C' col = tok (l16), row = och (quad*4+r). x residual read as 16B vec.
  f32x4 yv[8];
  {
    float biasp[4];
#pragma unroll
    for (int r = 0; r < 4; ++r) biasp[r] = ldS(b_proj, isf, wv * 16 + quad * 4 + r);
    for (int nt = 0; nt < 8; ++nt) {
      f32x4 acc = fzero4();
#pragma unroll
      for (int kt = 0; kt < 3; ++kt) {
        const int c0 = kt * 32 + quad * 8;
        const int h2 = c0 >> 4, off = c0 & 15;
        bf16x8 bo = ld8(smQ + h2 * QHW + (nt * 16 + l16) * QH_STR + off);
        acc = mfma16(bp[kt], bo, acc);
      }
      const size_t base = (size_t)tokp[nt * 16 + l16] * C_DIM + wv * 16 + quad * 4;
      f32x4 xr;
      if (isf) {
        xr = *(const f32x4*)((const float*)x + base);
      } else {
        u16x4 u = *(const u16x4*)((const unsigned short*)x + base);
#pragma unroll
        for (int j = 0; j < 4; ++j) xr[j] = bf2f(u[j]);
      }
#pragma unroll
      for (int r = 0; r < 4; ++r)
        yv[nt][r] = scrub(xr[r]) + acc[r] + biasp[r];
    }
  }
  __syncthreads();  // bar: smQ attn-out reads done -> red region writable

  // ---- LN2: per-token stats. thread holds (och=quad*4+r, tok=nt*16+l16) ----
  float* fred = (float*)(smQ + 13312);   // [128][6] float2 (sum, sumsq)
  float* fmr  = (float*)(smQ + 16384);   // [128] float2 (mean, rstd)
  {
    for (int nt = 0; nt < 8; ++nt) {
      float s  = yv[nt][0] + yv[nt][1] + yv[nt][2] + yv[nt][3];
      float s2 = yv[nt][0] * yv[nt][0] + yv[nt][1] * yv[nt][1]
               + yv[nt][2] * yv[nt][2] + yv[nt][3] * yv[nt][3];
      s  += __shfl_xor(s, 16, 64);  s2 += __shfl_xor(s2, 16, 64);
      s  += __shfl_xor(s, 32, 64);  s2 += __shfl_xor(s2, 32, 64);
      if (quad == 0) {
        float2 p; p.x = s; p.y = s2;
        ((float2*)fred)[(nt * 16 + l16) * 6 + wv] = p;
      }
    }
  }
  __syncthreads();
  if (t < 128) {
    float s = 0.f, s2 = 0.f;
#pragma unroll
    for (int w = 0; w < 6; ++w) {
      float2 p = ((float2*)fred)[t * 6 + w];
      s += p.x; s2 += p.y;
    }
    float mean = s * (1.0f / 96.0f);
    float var = fmaxf(s2 * (1.0f / 96.0f) - mean * mean, 0.0f);
    float2 mr; mr.x = mean; mr.y = rsqrtf(var + 1e-5f);
    ((float2*)fmr)[t] = mr;
  }
  __syncthreads();

  // ---- z = LN2(y)*g2+b2 -> smA [128][104] (A-region scratch is dead) ----
  {
    float g2v[4], b2v[4];
#pragma unroll
    for (int r = 0; r < 4; ++r) {
      g2v[r] = ldS(g2, isf, wv * 16 + quad * 4 + r);
      b2v[r] = ldS(b2, isf, wv * 16 + quad * 4 + r);
    }
    for (int nt = 0; nt < 8; ++nt) {
      float2 mr = ((float2*)fmr)[nt * 16 + l16];
      float z0 = (yv[nt][0] - mr.x) * mr.y * g2v[0] + b2v[0];
      float z1 = (yv[nt][1] - mr.x) * mr.y * g2v[1] + b2v[1];
      float z2 = (yv[nt][2] - mr.x) * mr.y * g2v[2] + b2v[2];
      float z3 = (yv[nt][3] - mr.x) * mr.y * g2v[3] + b2v[3];
      st_pk4(&smA[(nt * 16 + l16) * XO_STR + wv * 16 + quad * 4], z0, z1, z2, z3);
    }
  }
  __syncthreads();

  // ---- MLP: 4 chunks of 96 hidden; h via smQ[0..13312) [128][104] ----
  f32x4 acc2[8];
#pragma unroll
  for (int nt = 0; nt < 8; ++nt) acc2[nt] = fzero4();
  unsigned short* hbuf = smQ;

  for (int c = 0; c < 4; ++c) {
    const int hb = c * 96 + wv * 16;
    bf16x8 a1[3], a2[3];
#pragma unroll
    for (int kt = 0; kt < 3; ++kt) {
      a1[kt] = ld8G(w_fc1, isf, (size_t)(hb + l16) * C_DIM + kt * 32 + quad * 8);
      a2[kt] = ld8G(w_fc2, isf, (size_t)(wv * 16 + l16) * 384 + c * 96 + kt * 32 + quad * 8);
    }
    float b1v[4];
#pragma unroll
    for (int r = 0; r < 4; ++r) b1v[r] = ldS(b_fc1, isf, hb + quad * 4 + r);
    // fc1 transposed: C (hidden=quad*4+r, tok=l16); packed b64 h-stores
#pragma unroll
    for (int nt = 0; nt < 8; ++nt) {
      f32x4 acc = fzero4();
#pragma unroll
      for (int kt = 0; kt < 3; ++kt) {
        bf16x8 bz = ld8(smA + (nt * 16 + l16) * XO_STR + kt * 32 + quad * 8);
        acc = mfma16(a1[kt], bz, acc);
      }
      float g0 = gelu_f(acc[0] + b1v[0]);
      float g1v = gelu_f(acc[1] + b1v[1]);
      float g2x = gelu_f(acc[2] + b1v[2]);
      float g3 = gelu_f(acc[3] + b1v[3]);
      st_pk4(&hbuf[(nt * 16 + l16) * XO_STR + wv * 16 + quad * 4], g0, g1v, g2x, g3);
    }
    __syncthreads();
    // fc2 transposed partial: C (och=quad*4+r, tok=l16), acc into regs
#pragma unroll
    for (int nt = 0; nt < 8; ++nt) {
#pragma unroll
      for (int kt = 0; kt < 3; ++kt) {
        bf16x8 bh = ld8(hbuf + (nt * 16 + l16) * XO_STR + kt * 32 + quad * 8);
        acc2[nt] = mfma16(a2[kt], bh, acc2[nt]);
      }
    }
    if (c < 3) __syncthreads();
  }

  // ---- final: out = y + z_mlp + b_fc2; 16B scattered stores ----
  {
    float b2o[4];
#pragma unroll
    for (int r = 0; r < 4; ++r) b2o[r] = ldS(b_fc2, isf, wv * 16 + quad * 4 + r);
    for (int nt = 0; nt < 8; ++nt) {
      const size_t base = (size_t)tokp[nt * 16 + l16] * C_DIM + wv * 16 + quad * 4;
      if (isf) {
        f32x4 o4;
#pragma unroll
        for (int r = 0; r < 4; ++r) o4[r] = yv[nt][r] + acc2[nt][r] + b2o[r];
        *(f32x4*)((float*)y + base) = o4;
      } else {
        u16x4 u;
#pragma unroll
        for (int r = 0; r < 4; ++r) u[r] = f2bf(yv[nt][r] + acc2[nt][r] + b2o[r]);
        *(u16x4*)((unsigned short*)y + base) = u;
      }
    }
  }
}

// =====================================================================
extern "C" void kernel_launch(void* const* d_in, const int* in_sizes, int n_in,
                              void* d_out, int out_size, void* d_ws, size_t ws_size,
                              hipStream_t stream) {
  const void* x      = d_in[0];
  // d_in[1] = attn_mask (recomputed analytically; unused)
  const void* g1     = d_in[2];
  const void* b1     = d_in[3];
  const void* w_qkv  = d_in[4];
  const void* b_qkv  = d_in[5];
  const void* w_proj = d_in[6];
  const void* b_proj = d_in[7];
  const void* g2     = d_in[8];
  const void* b2     = d_in[9];
  const void* w_fc1  = d_in[10];
  const void* b_fc1  = d_in[11];
  const void* w_fc2  = d_in[12];
  const void* b_fc2  = d_in[13];
  int* flag = (int*)d_ws;

  dtype_sniff<<<1, 64, 0, stream>>>((const unsigned short*)x, flag);
  swin_block_kernel<<<1024, 768, 0, stream>>>(
      x, g1, b1, w_qkv, b_qkv, w_proj, b_proj,
      g2, b2, w_fc1, b_fc1, w_fc2, b_fc2, d_out, flag);
}